// Round 9
// baseline (159.117 us; speedup 1.0000x reference)
//
#include <hip/hip_runtime.h>

#define H 384
#define W 384
#define HWSZ (H * W)
#define NB 16
#define ND 2048
#define DD 256

// workspace byte offsets (all 256-aligned)
#define OFF_RESP  256
#define OFF_CVAL  9437440
#define OFF_CPOS  9584896
#define OFF_DESCB 9732352     // fp8 descriptors: 16*2048*256 = 8.4 MB
#define OFF_INV   26509568
#define OFF_PSOFT 26640640    // 576 floats
#define OFF_PGEMM 26643200    // 2176 floats
#define OFF_PCORN 26652160    // 16 floats
#define OFF_CNT   26652224    // arrival counters: gemm+softplus at cnt[i*64]
                              // (i=0..7, 256B apart); topk at cnt[512]

__device__ __forceinline__ int clampi(int v) { return v < 0 ? 0 : (v > 383 ? 383 : v); }
__device__ __forceinline__ int refl(int v) { return v < 0 ? -v : (v >= 384 ? 766 - v : v); }

// fp32 -> OCP e4m3fn with RNE. Layout: [s:1][eeee:4][mmm:3] -> s<<7 | e<<3 | m.
__device__ __forceinline__ unsigned f2e4m3(float x) {
  float a = fabsf(x);
  unsigned s = (__float_as_uint(x) >> 31) << 7;
  if (a >= 448.f) return s | 0x7E;
  if (a < 0.015625f) {
    int m = (int)rintf(a * 512.f);
    return s | (unsigned)m;
  }
  unsigned u = __float_as_uint(a);
  u += 0x7FFFF + ((u >> 20) & 1);
  unsigned e = (u >> 23) - 120;
  unsigned m = (u >> 20) & 7;
  return s | (e << 3) | m;
}

typedef float f32x4 __attribute__((ext_vector_type(4)));

__device__ __forceinline__ void load_lds16(const void* g, void* l) {
  __builtin_amdgcn_global_load_lds((const __attribute__((address_space(1))) void*)g,
                                   (__attribute__((address_space(3))) void*)l, 16, 0, 0);
}

// fence-free cross-XCD publish/read: relaxed agent-scope ops hit the LLC
// per-line — no L2 writeback flush (the R2/R5 poison was per-block fences;
// R7's poison was 2176 RMWs on ONE line — fixed here with 8 split lines).
__device__ __forceinline__ void pubf(float* p, float v) {
  __hip_atomic_store(p, v, __ATOMIC_RELAXED, __HIP_MEMORY_SCOPE_AGENT);
}
__device__ __forceinline__ float rdf(const float* p) {
  return __hip_atomic_load(p, __ATOMIC_RELAXED, __HIP_MEMORY_SCOPE_AGENT);
}

// ---------------------------------------------------------------------------
// STAGE 1: resp (blocks 0..2303) || prep_desc (blocks 2304..10495).
// (byte-identical to the 152.4 µs R6 version)
// ---------------------------------------------------------------------------
__global__ __launch_bounds__(256) void stage1_kernel(const float* __restrict__ imgs,
                                                     float* __restrict__ resp,
                                                     const float* __restrict__ desc,
                                                     unsigned char* __restrict__ descF8,
                                                     float* __restrict__ invn) {
  __shared__ float pbuf[4448];   // p0/p1/p2: 3 x [38][39]
  __shared__ float ubuf[3648];   // union: gl[40][41] (phases 0-1) / t0..t2 [38][32] (2-3)
  float* p0 = pbuf;
  float* p1 = pbuf + 1482;
  float* p2 = pbuf + 2964;
  float* glf = ubuf;             // stride 41
  float* t0 = ubuf;              // stride 32
  float* t1 = ubuf + 1216;
  float* t2 = ubuf + 2432;

  if (blockIdx.x >= 2304) {
    // ---- prep_desc: fp32 -> fp8 e4m3 + per-row inverse norm ----
    int wave = threadIdx.x >> 6, lane = threadIdx.x & 63;
    int row = (blockIdx.x - 2304) * 4 + wave;
    const float4* src = (const float4*)(desc + (size_t)row * DD);
    float4 v = src[lane];
    unsigned pk = f2e4m3(v.x) | (f2e4m3(v.y) << 8) | (f2e4m3(v.z) << 16) | (f2e4m3(v.w) << 24);
    ((unsigned*)(descF8 + (size_t)row * DD))[lane] = pk;
    float ss = v.x * v.x + v.y * v.y + v.z * v.z + v.w * v.w;
    for (int off = 32; off; off >>= 1) ss += __shfl_down(ss, off, 64);
    if (lane == 0) invn[row] = 1.f / fmaxf(sqrtf(ss), 1e-4f);
    return;
  }

  // ---- resp: gray -> sobel(edge) -> products -> 7x7 gauss(reflect) -> GFTT ----
  const float GW[7] = {0.0044330482f, 0.0540055826f, 0.2420362294f, 0.3990502160f,
                       0.2420362294f, 0.0540055826f, 0.0044330482f};
  int bid = blockIdx.x;
  int b = bid / 144;
  int t = bid % 144;
  int Y0 = (t / 12) * 32, X0 = (t % 12) * 32;
  const float* ib = imgs + (size_t)b * 3 * HWSZ;

  for (int i = threadIdx.x; i < 1600; i += 256) {
    int r = i / 40, c = i % 40;
    int gy = clampi(Y0 - 4 + r), gx = clampi(X0 - 4 + c);
    const float* p = ib + gy * W + gx;
    glf[r * 41 + c] = 0.299f * p[0] + 0.587f * p[HWSZ] + 0.114f * p[2 * HWSZ];
  }
  __syncthreads();

  bool interior = (X0 >= 32 && X0 <= 320 && Y0 >= 32 && Y0 <= 320);

  if (interior) {
    for (int i = threadIdx.x; i < 1444; i += 256) {
      int r = i / 38, c = i % 38;
      const float* g0 = glf + r * 41 + c;
      float a = g0[0],  bb = g0[1],  cc = g0[2];
      float d = g0[41],              e = g0[43];
      float f = g0[82], g = g0[83],  h = g0[84];
      float dx = 0.125f * ((cc - a) + 2.f * (e - d) + (h - f));
      float dy = 0.125f * ((f - a) + 2.f * (g - bb) + (h - cc));
      p0[r * 39 + c] = dx * dx;
      p1[r * 39 + c] = dy * dy;
      p2[r * 39 + c] = dx * dy;
    }
  } else {
    for (int i = threadIdx.x; i < 1444; i += 256) {
      int r = i / 38, c = i % 38;
      int py = refl(Y0 - 3 + r), px = refl(X0 - 3 + c);
      int ym = clampi(py - 1) - (Y0 - 4), y0 = py - (Y0 - 4), yp = clampi(py + 1) - (Y0 - 4);
      int xm = clampi(px - 1) - (X0 - 4), x0 = px - (X0 - 4), xp = clampi(px + 1) - (X0 - 4);
      float a = glf[ym * 41 + xm], bb = glf[ym * 41 + x0], cc = glf[ym * 41 + xp];
      float d = glf[y0 * 41 + xm], e = glf[y0 * 41 + xp];
      float f = glf[yp * 41 + xm], g = glf[yp * 41 + x0], h = glf[yp * 41 + xp];
      float dx = 0.125f * ((cc - a) + 2.f * (e - d) + (h - f));
      float dy = 0.125f * ((f - a) + 2.f * (g - bb) + (h - cc));
      p0[r * 39 + c] = dx * dx;
      p1[r * 39 + c] = dy * dy;
      p2[r * 39 + c] = dx * dy;
    }
  }
  __syncthreads();

  for (int g = threadIdx.x; g < 304; g += 256) {
    int r = g >> 3, c0 = (g & 7) * 4;
    {
      float a[10];
#pragma unroll
      for (int dc = 0; dc < 10; dc++) a[dc] = p0[r * 39 + c0 + dc];
#pragma unroll
      for (int k = 0; k < 4; k++) {
        float sv = 0.f;
#pragma unroll
        for (int j = 0; j < 7; j++) sv += GW[j] * a[k + j];
        t0[r * 32 + c0 + k] = sv;
      }
    }
    {
      float a[10];
#pragma unroll
      for (int dc = 0; dc < 10; dc++) a[dc] = p1[r * 39 + c0 + dc];
#pragma unroll
      for (int k = 0; k < 4; k++) {
        float sv = 0.f;
#pragma unroll
        for (int j = 0; j < 7; j++) sv += GW[j] * a[k + j];
        t1[r * 32 + c0 + k] = sv;
      }
    }
    {
      float a[10];
#pragma unroll
      for (int dc = 0; dc < 10; dc++) a[dc] = p2[r * 39 + c0 + dc];
#pragma unroll
      for (int k = 0; k < 4; k++) {
        float sv = 0.f;
#pragma unroll
        for (int j = 0; j < 7; j++) sv += GW[j] * a[k + j];
        t2[r * 32 + c0 + k] = sv;
      }
    }
  }
  __syncthreads();

  {
    int r0 = (threadIdx.x >> 5) * 4, c = threadIdx.x & 31;
    float s0[4], s1[4], s2[4];
    {
      float a[10];
#pragma unroll
      for (int dr = 0; dr < 10; dr++) a[dr] = t0[(r0 + dr) * 32 + c];
#pragma unroll
      for (int k = 0; k < 4; k++) {
        float sv = 0.f;
#pragma unroll
        for (int j = 0; j < 7; j++) sv += GW[j] * a[k + j];
        s0[k] = sv;
      }
    }
    {
      float a[10];
#pragma unroll
      for (int dr = 0; dr < 10; dr++) a[dr] = t1[(r0 + dr) * 32 + c];
#pragma unroll
      for (int k = 0; k < 4; k++) {
        float sv = 0.f;
#pragma unroll
        for (int j = 0; j < 7; j++) sv += GW[j] * a[k + j];
        s1[k] = sv;
      }
    }
    {
      float a[10];
#pragma unroll
      for (int dr = 0; dr < 10; dr++) a[dr] = t2[(r0 + dr) * 32 + c];
#pragma unroll
      for (int k = 0; k < 4; k++) {
        float sv = 0.f;
#pragma unroll
        for (int j = 0; j < 7; j++) sv += GW[j] * a[k + j];
        s2[k] = sv;
      }
    }
#pragma unroll
    for (int k = 0; k < 4; k++) {
      float tr = s0[k] + s1[k];
      float det = s0[k] * s1[k] - s2[k] * s2[k];
      float disc = tr * tr - 4.f * det;
      float rv = 0.5f * (tr - sqrtf(fabsf(disc)));
      resp[(size_t)b * HWSZ + (Y0 + r0 + k) * W + (X0 + c)] = rv;
    }
  }
}

// ---------------------------------------------------------------------------
// STAGE 2: nms only, 64x32 tiles (1152 blocks, 18.8 KB LDS -> 8 blocks/CU).
// Block 0 re-arms stage3's arrival counters (plain stores; the kernel
// boundary's release/acquire makes them visible — belt-and-suspenders on
// top of the harness workspace fill).
// ---------------------------------------------------------------------------
__global__ __launch_bounds__(256) void stage2_kernel(const float* __restrict__ resp,
                                                     float* __restrict__ cval,
                                                     unsigned* __restrict__ cpos,
                                                     int* __restrict__ cnt) {
  __shared__ float rl[68][37];    // 10064 B
  __shared__ float rmx[68][32];   // 8704 B

  if (blockIdx.x == 0 && threadIdx.x < 9) cnt[threadIdx.x * 64] = 0;

  int bid = blockIdx.x;
  int b = bid / 72;
  int t = bid % 72;
  int Y0 = (t / 12) * 64, X0 = (t % 12) * 32;
  const float* rb = resp + (size_t)b * HWSZ;

  for (int i = threadIdx.x; i < 68 * 36; i += 256) {
    int r = i / 36, c = i % 36;
    int gy = Y0 - 2 + r, gx = X0 - 2 + c;
    float v = -INFINITY;
    if (gy >= 0 && gy < H && gx >= 0 && gx < W) v = rb[gy * W + gx];
    rl[r][c] = v;
  }
  __syncthreads();

  // horizontal 5-max: 68 rows x 32 output cols
  for (int i = threadIdx.x; i < 68 * 32; i += 256) {
    int r = i / 32, c = i % 32;
    float m = rl[r][c];
    m = fmaxf(m, rl[r][c + 1]);
    m = fmaxf(m, rl[r][c + 2]);
    m = fmaxf(m, rl[r][c + 3]);
    m = fmaxf(m, rl[r][c + 4]);
    rmx[r][c] = m;
  }
  __syncthreads();

  // vertical 5-max + nms verdict written in place into rl's center
  for (int i = threadIdx.x; i < 2048; i += 256) {
    int r = i / 32, c = i % 32;
    float m = rmx[r][c];
    m = fmaxf(m, rmx[r + 1][c]);
    m = fmaxf(m, rmx[r + 2][c]);
    m = fmaxf(m, rmx[r + 3][c]);
    m = fmaxf(m, rmx[r + 4][c]);
    float v = rl[r + 2][c + 2];
    rl[r + 2][c + 2] = (v == m) ? v : 0.f;
  }
  __syncthreads();

  if (threadIdx.x < 32) {
    int bi = threadIdx.x >> 2, bj = threadIdx.x & 3;   // 8x4 sub-blocks of 8x8
    float bv = 0.f;
    unsigned bp = 0;
    for (int rr = 0; rr < 8; rr++)
      for (int cc = 0; cc < 8; cc++) {
        float v = rl[bi * 8 + rr + 2][bj * 8 + cc + 2];
        if (v > bv) { bv = v; bp = (unsigned)((Y0 + bi * 8 + rr) * W + (X0 + bj * 8 + cc)); }
      }
    int ci = b * 2304 + (Y0 / 8 + bi) * 48 + (X0 / 8 + bj);
    cval[ci] = bv;
    cpos[ci] = bp;
  }
}

// ---------------------------------------------------------------------------
// STAGE 3: topk (0..15) || softplus (16..591, hides in GEMM ramp) ||
// fp8 Gram-GEMM (592..2767; 592%8==0 keeps the XCD-chunk map) + folded
// finalize. Arrivals: gemm+softplus bump cnt[(bid&7)*64] (8 lines, 256 B
// apart -> ~344 RMWs/line staggered over the GEMM span, no serialization);
// topk bumps cnt[512]. The 16th topk arriver spins (s_sleep, 1 slot) until
// gemm+softplus count = 2752, then runs the finalize reduction in the exact
// index order of the old kernel -> bitwise identical. Publishes are relaxed
// agent-scope stores + vmcnt(0) before the bump — zero fences anywhere.
// LDS: one 32768-byte union -> 5 blocks/CU.
// ---------------------------------------------------------------------------
__global__ __launch_bounds__(256) void stage3_kernel(const float* __restrict__ cval,
                                                     const unsigned* __restrict__ cpos,
                                                     const float* __restrict__ sd,
                                                     float* __restrict__ pcorn,
                                                     const unsigned char* __restrict__ descF8,
                                                     const float* __restrict__ invn,
                                                     float* __restrict__ pgemm,
                                                     float* __restrict__ psoft,
                                                     int* __restrict__ cnt,
                                                     float* __restrict__ out) {
  alignas(16) __shared__ char smem[32768];
  int tid = threadIdx.x;

  if (blockIdx.x < 16) {
    // ---- topk radix-select for batch b + last-arriver finalize ----
    int* hist = (int*)smem;                      // 1024 B
    int* pick = (int*)(smem + 1024);             // 8 B
    int* eqcnt = (int*)(smem + 1032);            // 4 B
    int* ri = (int*)(smem + 1040);               // 16 B
    unsigned* eqpos = (unsigned*)(smem + 1056);  // 1024 B
    float* r4 = (float*)(smem + 2080);           // 16 B
    int* finFlag = (int*)(smem + 2096);          // 4 B

    int b = blockIdx.x;
    int t = tid;
    int lane = t & 63;

    unsigned bits[9], pos[9];
#pragma unroll
    for (int q = 0; q < 9; q++) {
      int i = t + q * 256;
      unsigned vb = 0, p = 0;
      if (i < 2304) {
        float v = cval[b * 2304 + i];
        if (v > 0.f) { vb = __float_as_uint(v); p = cpos[b * 2304 + i]; }
      }
      bits[q] = vb; pos[q] = p;
    }

    int P = 0;
#pragma unroll
    for (int q = 0; q < 9; q++) P += (bits[q] != 0u);
    for (int off = 32; off; off >>= 1) P += __shfl_down(P, off, 64);
    if (lane == 0) ri[t >> 6] = P;
    __syncthreads();
    int Ptot = ri[0] + ri[1] + ri[2] + ri[3];

    float total = 0.f;
    if (Ptot > 0) {
      int K = Ptot < 200 ? Ptot : 200;

      unsigned prefix = 0;
      int krem = K;
      for (int shift = 24; shift >= 0; shift -= 8) {
        hist[t] = 0;
        __syncthreads();
#pragma unroll
        for (int q = 0; q < 9; q++) {
          if (bits[q] != 0u &&
              (shift == 24 || (bits[q] >> (shift + 8)) == (prefix >> (shift + 8))))
            atomicAdd(&hist[(bits[q] >> shift) & 0xFF], 1);
        }
        __syncthreads();
        if (t < 64) {
          int h0 = hist[4 * t], h1 = hist[4 * t + 1], h2 = hist[4 * t + 2], h3 = hist[4 * t + 3];
          int tot = h0 + h1 + h2 + h3;
          int acc = tot;
          for (int d = 1; d < 64; d <<= 1) {
            int o = __shfl_down(acc, d, 64);
            if (t + d < 64) acc += o;
          }
          int excl = acc - tot;
          int G3 = excl, G2 = excl + h3, G1 = excl + h3 + h2, G0 = excl + h3 + h2 + h1;
          if (G0 < krem && G0 + h0 >= krem) { pick[0] = 4 * t;     pick[1] = G0; }
          if (G1 < krem && G1 + h1 >= krem) { pick[0] = 4 * t + 1; pick[1] = G1; }
          if (G2 < krem && G2 + h2 >= krem) { pick[0] = 4 * t + 2; pick[1] = G2; }
          if (G3 < krem && G3 + h3 >= krem) { pick[0] = 4 * t + 3; pick[1] = G3; }
        }
        __syncthreads();
        prefix |= ((unsigned)pick[0]) << shift;
        krem -= pick[1];
        __syncthreads();
      }

      if (t == 0) *eqcnt = 0;
      __syncthreads();
      float s = 0.f;
#pragma unroll
      for (int q = 0; q < 9; q++) {
        if (bits[q] > prefix) s += sd[(size_t)b * HWSZ + pos[q]];
        else if (bits[q] != 0u && bits[q] == prefix) {
          int idx = atomicAdd(eqcnt, 1);
          if (idx < 256) eqpos[idx] = pos[q];
        }
      }
      __syncthreads();
      int m = *eqcnt;
      if (m <= krem) {
        if (t < m) s += sd[(size_t)b * HWSZ + eqpos[t]];
      } else {
        int mm = m < 256 ? m : 256;
        if (t < mm) {
          unsigned p = eqpos[t];
          int rank = 0;
          for (int u = 0; u < mm; u++) rank += (eqpos[u] < p);
          if (rank < krem) s += sd[(size_t)b * HWSZ + p];
        }
      }
      for (int off = 32; off; off >>= 1) s += __shfl_down(s, off, 64);
      if (lane == 0) r4[t >> 6] = s;
      __syncthreads();
      total = r4[0] + r4[1] + r4[2] + r4[3];
    }

    if (t == 0) {
      pubf(&pcorn[b], total);
      asm volatile("s_waitcnt vmcnt(0)" ::: "memory");
      int arr = __hip_atomic_fetch_add(&cnt[512], 1, __ATOMIC_RELAXED, __HIP_MEMORY_SCOPE_AGENT);
      *finFlag = (arr == 15);
      if (arr == 15) {
        for (;;) {
          int sall = 0;
#pragma unroll
          for (int i = 0; i < 8; i++)
            sall += __hip_atomic_load(&cnt[i * 64], __ATOMIC_RELAXED, __HIP_MEMORY_SCOPE_AGENT);
          if (sall >= 2752) break;
          __builtin_amdgcn_s_sleep(16);
        }
      }
    }
    __syncthreads();
    if (!*finFlag) return;

    // ---- finalize (identical summation order to the old finalize kernel) ----
    float bce = 0.f;
    for (int i = t; i < 576; i += 256) bce += rdf(&psoft[i]);
    if (t < 16) bce -= rdf(&pcorn[t]);
    float g = 0.f;
    for (int i = t; i < 2176; i += 256) g += rdf(&pgemm[i]);
    float v = bce * (1.f / 2359296.f) + g * (1.f / 67108864.f);
    for (int off = 32; off; off >>= 1) v += __shfl_down(v, off, 64);
    if (lane == 0) r4[t >> 6] = v;
    __syncthreads();
    if (t == 0) out[0] = r4[0] + r4[1] + r4[2] + r4[3];
    return;
  }

  if (blockIdx.x < 592) {
    // ---- softplus partial sums (dispatched before GEMM -> hides in ramp) ----
    int sb = blockIdx.x - 16;
    float* r4 = (float*)smem;
    const float4* sd4 = (const float4*)sd;
    float s = 0.f;
    int base = sb * 256 + tid;
#pragma unroll
    for (int it = 0; it < 4; it++) {
      float4 v = sd4[base + it * 147456];
      s += fmaxf(v.x, 0.f) + log1pf(expf(-fabsf(v.x))) +
           fmaxf(v.y, 0.f) + log1pf(expf(-fabsf(v.y))) +
           fmaxf(v.z, 0.f) + log1pf(expf(-fabsf(v.z))) +
           fmaxf(v.w, 0.f) + log1pf(expf(-fabsf(v.w)));
    }
    for (int off = 32; off; off >>= 1) s += __shfl_down(s, off, 64);
    if ((tid & 63) == 0) r4[tid >> 6] = s;
    __syncthreads();
    if (tid == 0) {
      pubf(&psoft[sb], r4[0] + r4[1] + r4[2] + r4[3]);
      asm volatile("s_waitcnt vmcnt(0)" ::: "memory");
      __hip_atomic_fetch_add(&cnt[(blockIdx.x & 7) * 64], 1,
                             __ATOMIC_RELAXED, __HIP_MEMORY_SCOPE_AGENT);
    }
    return;
  }

  // ---- fp8 Gram-GEMM with relu-sum epilogue; swizzled LDS ----
  char* lA = smem;
  char* lB = smem + 16384;

  int bxl = blockIdx.x - 592;               // 0..2175; 592%8==0 keeps XCD map
  int bx = ((bxl & 7) * 272) + (bxl >> 3);  // contiguous 272-chunk per XCD
  int batch = bx / 136;
  int rem = bx % 136;
  int ti = 0, rowlen = 16;
  while (rem >= rowlen) { rem -= rowlen; rowlen--; ti++; }
  int tj = ti + rem;

  const unsigned char* Ab = descF8 + (size_t)batch * ND * DD;
  const float* inv = invn + batch * ND;
  int I0 = ti * 128, J0 = tj * 128;

  int wave = tid >> 6, lane = tid & 63;
  int rm = lane & 15, kq = lane >> 4;
  int wr = wave >> 1, wc = wave & 1;
  int lrow = lane >> 3;
  int lcolb = ((lane & 7) ^ lrow) << 4;   // swizzled source column (bytes)
  int cx = rm & 7;                        // read-side swizzle key

  f32x4 accf[4][4];
#pragma unroll
  for (int m = 0; m < 4; m++)
#pragma unroll
    for (int n = 0; n < 4; n++) accf[m][n] = (f32x4){0.f, 0.f, 0.f, 0.f};

  for (int k0 = 0; k0 < DD; k0 += 128) {
#pragma unroll
    for (int q = 0; q < 4; q++) {
      int chunk = wave * 4 + q;
      load_lds16(Ab + (size_t)(I0 + chunk * 8 + lrow) * DD + k0 + lcolb, lA + chunk * 1024);
      load_lds16(Ab + (size_t)(J0 + chunk * 8 + lrow) * DD + k0 + lcolb, lB + chunk * 1024);
    }
    __syncthreads();
#pragma unroll
    for (int kk = 0; kk < 128; kk += 32) {
      long af[4], bfr[4];
      int koff = kk + kq * 8;
      int pcol = ((((koff >> 4) ^ cx) << 4) | (koff & 8));
#pragma unroll
      for (int m = 0; m < 4; m++)
        af[m] = *reinterpret_cast<const long*>(lA + (wr * 64 + m * 16 + rm) * 128 + pcol);
#pragma unroll
      for (int n = 0; n < 4; n++)
        bfr[n] = *reinterpret_cast<const long*>(lB + (wc * 64 + n * 16 + rm) * 128 + pcol);
#pragma unroll
      for (int m = 0; m < 4; m++)
#pragma unroll
        for (int n = 0; n < 4; n++)
          accf[m][n] = __builtin_amdgcn_mfma_f32_16x16x32_fp8_fp8(af[m], bfr[n], accf[m][n], 0, 0, 0);
    }
    __syncthreads();
  }

  float wgt = (ti == tj) ? 1.f : 2.f;
  float invC[4];
#pragma unroll
  for (int n = 0; n < 4; n++) invC[n] = inv[J0 + wc * 64 + n * 16 + rm];
  float psum = 0.f;
#pragma unroll
  for (int m = 0; m < 4; m++) {
#pragma unroll
    for (int r = 0; r < 4; r++) {
      float invR = inv[I0 + wr * 64 + m * 16 + kq * 4 + r];
#pragma unroll
      for (int n = 0; n < 4; n++) psum += fmaxf(accf[m][n][r] * invR * invC[n], 0.f);
    }
  }
  psum *= wgt;
  for (int off = 32; off; off >>= 1) psum += __shfl_down(psum, off, 64);
  float* r4 = (float*)smem;   // overlays dead lA (k-loop ended with a barrier)
  if (lane == 0) r4[wave] = psum;
  __syncthreads();
  if (tid == 0) {
    pubf(&pgemm[bx], r4[0] + r4[1] + r4[2] + r4[3]);
    asm volatile("s_waitcnt vmcnt(0)" ::: "memory");
    __hip_atomic_fetch_add(&cnt[(blockIdx.x & 7) * 64], 1,
                           __ATOMIC_RELAXED, __HIP_MEMORY_SCOPE_AGENT);
  }
}

extern "C" void kernel_launch(void* const* d_in, const int* in_sizes, int n_in,
                              void* d_out, int out_size, void* d_ws, size_t ws_size,
                              hipStream_t stream) {
  (void)in_sizes; (void)n_in; (void)out_size; (void)ws_size;
  const float* desc = (const float*)d_in[0];
  const float* sd = (const float*)d_in[2];
  const float* imgs = (const float*)d_in[3];
  float* out = (float*)d_out;

  char* w = (char*)d_ws;
  float* resp = (float*)(w + OFF_RESP);
  float* cval = (float*)(w + OFF_CVAL);
  unsigned* cpos = (unsigned*)(w + OFF_CPOS);
  unsigned char* descF8 = (unsigned char*)(w + OFF_DESCB);
  float* invn = (float*)(w + OFF_INV);
  float* psoft = (float*)(w + OFF_PSOFT);
  float* pgemm = (float*)(w + OFF_PGEMM);
  float* pcorn = (float*)(w + OFF_PCORN);
  int* cnt = (int*)(w + OFF_CNT);

  stage1_kernel<<<10496, 256, 0, stream>>>(imgs, resp, desc, descF8, invn);
  stage2_kernel<<<1152, 256, 0, stream>>>(resp, cval, cpos, cnt);
  stage3_kernel<<<2768, 256, 0, stream>>>(cval, cpos, sd, pcorn, descF8, invn,
                                          pgemm, psoft, cnt, out);
}

// Round 10
// 156.038 us; speedup vs baseline: 1.0197x; 1.0197x over previous
//
#include <hip/hip_runtime.h>

#define H 384
#define W 384
#define HWSZ (H * W)
#define NB 16
#define ND 2048
#define DD 256

// workspace byte offsets (all 256-aligned)
#define OFF_RESP  256
#define OFF_CVAL  9437440
#define OFF_CPOS  9584896
#define OFF_DESCB 9732352     // fp8 descriptors: 16*2048*256 = 8.4 MB
#define OFF_INV   26509568
#define OFF_PSOFT 26640640    // 576 floats
#define OFF_PGEMM 26643200    // 2176 floats
#define OFF_PCORN 26652160    // 16 floats

__device__ __forceinline__ int clampi(int v) { return v < 0 ? 0 : (v > 383 ? 383 : v); }
__device__ __forceinline__ int refl(int v) { return v < 0 ? -v : (v >= 384 ? 766 - v : v); }

// fp32 -> OCP e4m3fn with RNE. Layout: [s:1][eeee:4][mmm:3] -> s<<7 | e<<3 | m.
__device__ __forceinline__ unsigned f2e4m3(float x) {
  float a = fabsf(x);
  unsigned s = (__float_as_uint(x) >> 31) << 7;
  if (a >= 448.f) return s | 0x7E;
  if (a < 0.015625f) {
    int m = (int)rintf(a * 512.f);
    return s | (unsigned)m;
  }
  unsigned u = __float_as_uint(a);
  u += 0x7FFFF + ((u >> 20) & 1);
  unsigned e = (u >> 23) - 120;
  unsigned m = (u >> 20) & 7;
  return s | (e << 3) | m;
}

typedef float f32x4 __attribute__((ext_vector_type(4)));

__device__ __forceinline__ void load_lds16(const void* g, void* l) {
  __builtin_amdgcn_global_load_lds((const __attribute__((address_space(1))) void*)g,
                                   (__attribute__((address_space(3))) void*)l, 16, 0, 0);
}

// ---------------------------------------------------------------------------
// STAGE 1: resp (blocks 0..2303) || prep_desc (blocks 2304..10495).
// (byte-identical to the 152.4 µs R6 version)
// ---------------------------------------------------------------------------
__global__ __launch_bounds__(256) void stage1_kernel(const float* __restrict__ imgs,
                                                     float* __restrict__ resp,
                                                     const float* __restrict__ desc,
                                                     unsigned char* __restrict__ descF8,
                                                     float* __restrict__ invn) {
  __shared__ float pbuf[4448];   // p0/p1/p2: 3 x [38][39]
  __shared__ float ubuf[3648];   // union: gl[40][41] (phases 0-1) / t0..t2 [38][32] (2-3)
  float* p0 = pbuf;
  float* p1 = pbuf + 1482;
  float* p2 = pbuf + 2964;
  float* glf = ubuf;             // stride 41
  float* t0 = ubuf;              // stride 32
  float* t1 = ubuf + 1216;
  float* t2 = ubuf + 2432;

  if (blockIdx.x >= 2304) {
    // ---- prep_desc: fp32 -> fp8 e4m3 + per-row inverse norm ----
    int wave = threadIdx.x >> 6, lane = threadIdx.x & 63;
    int row = (blockIdx.x - 2304) * 4 + wave;
    const float4* src = (const float4*)(desc + (size_t)row * DD);
    float4 v = src[lane];
    unsigned pk = f2e4m3(v.x) | (f2e4m3(v.y) << 8) | (f2e4m3(v.z) << 16) | (f2e4m3(v.w) << 24);
    ((unsigned*)(descF8 + (size_t)row * DD))[lane] = pk;
    float ss = v.x * v.x + v.y * v.y + v.z * v.z + v.w * v.w;
    for (int off = 32; off; off >>= 1) ss += __shfl_down(ss, off, 64);
    if (lane == 0) invn[row] = 1.f / fmaxf(sqrtf(ss), 1e-4f);
    return;
  }

  // ---- resp: gray -> sobel(edge) -> products -> 7x7 gauss(reflect) -> GFTT ----
  const float GW[7] = {0.0044330482f, 0.0540055826f, 0.2420362294f, 0.3990502160f,
                       0.2420362294f, 0.0540055826f, 0.0044330482f};
  int bid = blockIdx.x;
  int b = bid / 144;
  int t = bid % 144;
  int Y0 = (t / 12) * 32, X0 = (t % 12) * 32;
  const float* ib = imgs + (size_t)b * 3 * HWSZ;

  for (int i = threadIdx.x; i < 1600; i += 256) {
    int r = i / 40, c = i % 40;
    int gy = clampi(Y0 - 4 + r), gx = clampi(X0 - 4 + c);
    const float* p = ib + gy * W + gx;
    glf[r * 41 + c] = 0.299f * p[0] + 0.587f * p[HWSZ] + 0.114f * p[2 * HWSZ];
  }
  __syncthreads();

  bool interior = (X0 >= 32 && X0 <= 320 && Y0 >= 32 && Y0 <= 320);

  if (interior) {
    for (int i = threadIdx.x; i < 1444; i += 256) {
      int r = i / 38, c = i % 38;
      const float* g0 = glf + r * 41 + c;
      float a = g0[0],  bb = g0[1],  cc = g0[2];
      float d = g0[41],              e = g0[43];
      float f = g0[82], g = g0[83],  h = g0[84];
      float dx = 0.125f * ((cc - a) + 2.f * (e - d) + (h - f));
      float dy = 0.125f * ((f - a) + 2.f * (g - bb) + (h - cc));
      p0[r * 39 + c] = dx * dx;
      p1[r * 39 + c] = dy * dy;
      p2[r * 39 + c] = dx * dy;
    }
  } else {
    for (int i = threadIdx.x; i < 1444; i += 256) {
      int r = i / 38, c = i % 38;
      int py = refl(Y0 - 3 + r), px = refl(X0 - 3 + c);
      int ym = clampi(py - 1) - (Y0 - 4), y0 = py - (Y0 - 4), yp = clampi(py + 1) - (Y0 - 4);
      int xm = clampi(px - 1) - (X0 - 4), x0 = px - (X0 - 4), xp = clampi(px + 1) - (X0 - 4);
      float a = glf[ym * 41 + xm], bb = glf[ym * 41 + x0], cc = glf[ym * 41 + xp];
      float d = glf[y0 * 41 + xm], e = glf[y0 * 41 + xp];
      float f = glf[yp * 41 + xm], g = glf[yp * 41 + x0], h = glf[yp * 41 + xp];
      float dx = 0.125f * ((cc - a) + 2.f * (e - d) + (h - f));
      float dy = 0.125f * ((f - a) + 2.f * (g - bb) + (h - cc));
      p0[r * 39 + c] = dx * dx;
      p1[r * 39 + c] = dy * dy;
      p2[r * 39 + c] = dx * dy;
    }
  }
  __syncthreads();

  for (int g = threadIdx.x; g < 304; g += 256) {
    int r = g >> 3, c0 = (g & 7) * 4;
    {
      float a[10];
#pragma unroll
      for (int dc = 0; dc < 10; dc++) a[dc] = p0[r * 39 + c0 + dc];
#pragma unroll
      for (int k = 0; k < 4; k++) {
        float sv = 0.f;
#pragma unroll
        for (int j = 0; j < 7; j++) sv += GW[j] * a[k + j];
        t0[r * 32 + c0 + k] = sv;
      }
    }
    {
      float a[10];
#pragma unroll
      for (int dc = 0; dc < 10; dc++) a[dc] = p1[r * 39 + c0 + dc];
#pragma unroll
      for (int k = 0; k < 4; k++) {
        float sv = 0.f;
#pragma unroll
        for (int j = 0; j < 7; j++) sv += GW[j] * a[k + j];
        t1[r * 32 + c0 + k] = sv;
      }
    }
    {
      float a[10];
#pragma unroll
      for (int dc = 0; dc < 10; dc++) a[dc] = p2[r * 39 + c0 + dc];
#pragma unroll
      for (int k = 0; k < 4; k++) {
        float sv = 0.f;
#pragma unroll
        for (int j = 0; j < 7; j++) sv += GW[j] * a[k + j];
        t2[r * 32 + c0 + k] = sv;
      }
    }
  }
  __syncthreads();

  {
    int r0 = (threadIdx.x >> 5) * 4, c = threadIdx.x & 31;
    float s0[4], s1[4], s2[4];
    {
      float a[10];
#pragma unroll
      for (int dr = 0; dr < 10; dr++) a[dr] = t0[(r0 + dr) * 32 + c];
#pragma unroll
      for (int k = 0; k < 4; k++) {
        float sv = 0.f;
#pragma unroll
        for (int j = 0; j < 7; j++) sv += GW[j] * a[k + j];
        s0[k] = sv;
      }
    }
    {
      float a[10];
#pragma unroll
      for (int dr = 0; dr < 10; dr++) a[dr] = t1[(r0 + dr) * 32 + c];
#pragma unroll
      for (int k = 0; k < 4; k++) {
        float sv = 0.f;
#pragma unroll
        for (int j = 0; j < 7; j++) sv += GW[j] * a[k + j];
        s1[k] = sv;
      }
    }
    {
      float a[10];
#pragma unroll
      for (int dr = 0; dr < 10; dr++) a[dr] = t2[(r0 + dr) * 32 + c];
#pragma unroll
      for (int k = 0; k < 4; k++) {
        float sv = 0.f;
#pragma unroll
        for (int j = 0; j < 7; j++) sv += GW[j] * a[k + j];
        s2[k] = sv;
      }
    }
#pragma unroll
    for (int k = 0; k < 4; k++) {
      float tr = s0[k] + s1[k];
      float det = s0[k] * s1[k] - s2[k] * s2[k];
      float disc = tr * tr - 4.f * det;
      float rv = 0.5f * (tr - sqrtf(fabsf(disc)));
      resp[(size_t)b * HWSZ + (Y0 + r0 + k) * W + (X0 + c)] = rv;
    }
  }
}

// ---------------------------------------------------------------------------
// STAGE 2: nms only, 64x32 tiles (1152 blocks; 18.8 KB LDS -> 8 blocks/CU).
// Softplus moved to stage3's ramp (it has no consumer inside any kernel —
// psoft is read only by finalize, across a boundary). No sync anywhere.
// ---------------------------------------------------------------------------
__global__ __launch_bounds__(256) void stage2_kernel(const float* __restrict__ resp,
                                                     float* __restrict__ cval,
                                                     unsigned* __restrict__ cpos) {
  __shared__ float rl[68][37];    // 10064 B
  __shared__ float rmx[68][32];   // 8704 B

  int bid = blockIdx.x;
  int b = bid / 72;
  int t = bid % 72;
  int Y0 = (t / 12) * 64, X0 = (t % 12) * 32;
  const float* rb = resp + (size_t)b * HWSZ;

  for (int i = threadIdx.x; i < 68 * 36; i += 256) {
    int r = i / 36, c = i % 36;
    int gy = Y0 - 2 + r, gx = X0 - 2 + c;
    float v = -INFINITY;
    if (gy >= 0 && gy < H && gx >= 0 && gx < W) v = rb[gy * W + gx];
    rl[r][c] = v;
  }
  __syncthreads();

  // horizontal 5-max: 68 rows x 32 output cols
  for (int i = threadIdx.x; i < 68 * 32; i += 256) {
    int r = i / 32, c = i % 32;
    float m = rl[r][c];
    m = fmaxf(m, rl[r][c + 1]);
    m = fmaxf(m, rl[r][c + 2]);
    m = fmaxf(m, rl[r][c + 3]);
    m = fmaxf(m, rl[r][c + 4]);
    rmx[r][c] = m;
  }
  __syncthreads();

  // vertical 5-max + nms verdict written in place into rl's center
  for (int i = threadIdx.x; i < 2048; i += 256) {
    int r = i / 32, c = i % 32;
    float m = rmx[r][c];
    m = fmaxf(m, rmx[r + 1][c]);
    m = fmaxf(m, rmx[r + 2][c]);
    m = fmaxf(m, rmx[r + 3][c]);
    m = fmaxf(m, rmx[r + 4][c]);
    float v = rl[r + 2][c + 2];
    rl[r + 2][c + 2] = (v == m) ? v : 0.f;
  }
  __syncthreads();

  if (threadIdx.x < 32) {
    int bi = threadIdx.x >> 2, bj = threadIdx.x & 3;   // 8x4 sub-blocks of 8x8
    float bv = 0.f;
    unsigned bp = 0;
    for (int rr = 0; rr < 8; rr++)
      for (int cc = 0; cc < 8; cc++) {
        float v = rl[bi * 8 + rr + 2][bj * 8 + cc + 2];
        if (v > bv) { bv = v; bp = (unsigned)((Y0 + bi * 8 + rr) * W + (X0 + bj * 8 + cc)); }
      }
    int ci = b * 2304 + (Y0 / 8 + bi) * 48 + (X0 / 8 + bj);
    cval[ci] = bv;
    cpos[ci] = bp;
  }
}

// ---------------------------------------------------------------------------
// STAGE 3: topk (blocks 0..15) || softplus (16..591, vacates ramp slots in
// ~2 µs under the GEMM whale) || fp8 Gram-GEMM (592..2767; 592%8==0 keeps
// the XCD-chunk map). No cross-block sync of any kind. One 32768-byte LDS
// union -> 5 blocks/CU.
// ---------------------------------------------------------------------------
__global__ __launch_bounds__(256) void stage3_kernel(const float* __restrict__ cval,
                                                     const unsigned* __restrict__ cpos,
                                                     const float* __restrict__ sd,
                                                     float* __restrict__ pcorn,
                                                     const unsigned char* __restrict__ descF8,
                                                     const float* __restrict__ invn,
                                                     float* __restrict__ pgemm,
                                                     float* __restrict__ psoft) {
  alignas(16) __shared__ char smem[32768];
  int tid = threadIdx.x;

  if (blockIdx.x < 16) {
    // ---- topk radix-select for batch b ----
    int* hist = (int*)smem;                      // 1024 B
    int* pick = (int*)(smem + 1024);             // 8 B
    int* eqcnt = (int*)(smem + 1032);            // 4 B
    int* ri = (int*)(smem + 1040);               // 16 B
    unsigned* eqpos = (unsigned*)(smem + 1056);  // 1024 B
    float* r4 = (float*)(smem + 2080);           // 16 B

    int b = blockIdx.x;
    int t = tid;
    int lane = t & 63;

    unsigned bits[9], pos[9];
#pragma unroll
    for (int q = 0; q < 9; q++) {
      int i = t + q * 256;
      unsigned vb = 0, p = 0;
      if (i < 2304) {
        float v = cval[b * 2304 + i];
        if (v > 0.f) { vb = __float_as_uint(v); p = cpos[b * 2304 + i]; }
      }
      bits[q] = vb; pos[q] = p;
    }

    int P = 0;
#pragma unroll
    for (int q = 0; q < 9; q++) P += (bits[q] != 0u);
    for (int off = 32; off; off >>= 1) P += __shfl_down(P, off, 64);
    if (lane == 0) ri[t >> 6] = P;
    __syncthreads();
    int Ptot = ri[0] + ri[1] + ri[2] + ri[3];
    if (Ptot == 0) { if (t == 0) pcorn[b] = 0.f; return; }
    int K = Ptot < 200 ? Ptot : 200;

    unsigned prefix = 0;
    int krem = K;
    for (int shift = 24; shift >= 0; shift -= 8) {
      hist[t] = 0;
      __syncthreads();
#pragma unroll
      for (int q = 0; q < 9; q++) {
        if (bits[q] != 0u &&
            (shift == 24 || (bits[q] >> (shift + 8)) == (prefix >> (shift + 8))))
          atomicAdd(&hist[(bits[q] >> shift) & 0xFF], 1);
      }
      __syncthreads();
      if (t < 64) {
        int h0 = hist[4 * t], h1 = hist[4 * t + 1], h2 = hist[4 * t + 2], h3 = hist[4 * t + 3];
        int tot = h0 + h1 + h2 + h3;
        int acc = tot;
        for (int d = 1; d < 64; d <<= 1) {
          int o = __shfl_down(acc, d, 64);
          if (t + d < 64) acc += o;
        }
        int excl = acc - tot;
        int G3 = excl, G2 = excl + h3, G1 = excl + h3 + h2, G0 = excl + h3 + h2 + h1;
        if (G0 < krem && G0 + h0 >= krem) { pick[0] = 4 * t;     pick[1] = G0; }
        if (G1 < krem && G1 + h1 >= krem) { pick[0] = 4 * t + 1; pick[1] = G1; }
        if (G2 < krem && G2 + h2 >= krem) { pick[0] = 4 * t + 2; pick[1] = G2; }
        if (G3 < krem && G3 + h3 >= krem) { pick[0] = 4 * t + 3; pick[1] = G3; }
      }
      __syncthreads();
      prefix |= ((unsigned)pick[0]) << shift;
      krem -= pick[1];
      __syncthreads();
    }

    if (t == 0) *eqcnt = 0;
    __syncthreads();
    float s = 0.f;
#pragma unroll
    for (int q = 0; q < 9; q++) {
      if (bits[q] > prefix) s += sd[(size_t)b * HWSZ + pos[q]];
      else if (bits[q] != 0u && bits[q] == prefix) {
        int idx = atomicAdd(eqcnt, 1);
        if (idx < 256) eqpos[idx] = pos[q];
      }
    }
    __syncthreads();
    int m = *eqcnt;
    if (m <= krem) {
      if (t < m) s += sd[(size_t)b * HWSZ + eqpos[t]];
    } else {
      int mm = m < 256 ? m : 256;
      if (t < mm) {
        unsigned p = eqpos[t];
        int rank = 0;
        for (int u = 0; u < mm; u++) rank += (eqpos[u] < p);
        if (rank < krem) s += sd[(size_t)b * HWSZ + p];
      }
    }
    for (int off = 32; off; off >>= 1) s += __shfl_down(s, off, 64);
    if (lane == 0) r4[t >> 6] = s;
    __syncthreads();
    if (t == 0) pcorn[b] = r4[0] + r4[1] + r4[2] + r4[3];
    return;
  }

  if (blockIdx.x < 592) {
    // ---- softplus partial sums (identical math/order to the R6 version) ----
    int sb = blockIdx.x - 16;
    float* r4 = (float*)smem;
    const float4* sd4 = (const float4*)sd;
    float s = 0.f;
    int base = sb * 256 + tid;
#pragma unroll
    for (int it = 0; it < 4; it++) {
      float4 v = sd4[base + it * 147456];
      s += fmaxf(v.x, 0.f) + log1pf(expf(-fabsf(v.x))) +
           fmaxf(v.y, 0.f) + log1pf(expf(-fabsf(v.y))) +
           fmaxf(v.z, 0.f) + log1pf(expf(-fabsf(v.z))) +
           fmaxf(v.w, 0.f) + log1pf(expf(-fabsf(v.w)));
    }
    for (int off = 32; off; off >>= 1) s += __shfl_down(s, off, 64);
    if ((tid & 63) == 0) r4[tid >> 6] = s;
    __syncthreads();
    if (tid == 0) psoft[sb] = r4[0] + r4[1] + r4[2] + r4[3];
    return;
  }

  // ---- fp8 Gram-GEMM with relu-sum epilogue; swizzled LDS ----
  char* lA = smem;
  char* lB = smem + 16384;

  int bxl = blockIdx.x - 592;               // 0..2175; 592%8==0 keeps XCD map
  int bx = ((bxl & 7) * 272) + (bxl >> 3);  // contiguous 272-chunk per XCD
  int batch = bx / 136;
  int rem = bx % 136;
  int ti = 0, rowlen = 16;
  while (rem >= rowlen) { rem -= rowlen; rowlen--; ti++; }
  int tj = ti + rem;

  const unsigned char* Ab = descF8 + (size_t)batch * ND * DD;
  const float* inv = invn + batch * ND;
  int I0 = ti * 128, J0 = tj * 128;

  int wave = tid >> 6, lane = tid & 63;
  int rm = lane & 15, kq = lane >> 4;
  int wr = wave >> 1, wc = wave & 1;
  int lrow = lane >> 3;
  int lcolb = ((lane & 7) ^ lrow) << 4;   // swizzled source column (bytes)
  int cx = rm & 7;                        // read-side swizzle key

  f32x4 accf[4][4];
#pragma unroll
  for (int m = 0; m < 4; m++)
#pragma unroll
    for (int n = 0; n < 4; n++) accf[m][n] = (f32x4){0.f, 0.f, 0.f, 0.f};

  for (int k0 = 0; k0 < DD; k0 += 128) {
#pragma unroll
    for (int q = 0; q < 4; q++) {
      int chunk = wave * 4 + q;
      load_lds16(Ab + (size_t)(I0 + chunk * 8 + lrow) * DD + k0 + lcolb, lA + chunk * 1024);
      load_lds16(Ab + (size_t)(J0 + chunk * 8 + lrow) * DD + k0 + lcolb, lB + chunk * 1024);
    }
    __syncthreads();
#pragma unroll
    for (int kk = 0; kk < 128; kk += 32) {
      long af[4], bfr[4];
      int koff = kk + kq * 8;
      int pcol = ((((koff >> 4) ^ cx) << 4) | (koff & 8));
#pragma unroll
      for (int m = 0; m < 4; m++)
        af[m] = *reinterpret_cast<const long*>(lA + (wr * 64 + m * 16 + rm) * 128 + pcol);
#pragma unroll
      for (int n = 0; n < 4; n++)
        bfr[n] = *reinterpret_cast<const long*>(lB + (wc * 64 + n * 16 + rm) * 128 + pcol);
#pragma unroll
      for (int m = 0; m < 4; m++)
#pragma unroll
        for (int n = 0; n < 4; n++)
          accf[m][n] = __builtin_amdgcn_mfma_f32_16x16x32_fp8_fp8(af[m], bfr[n], accf[m][n], 0, 0, 0);
    }
    __syncthreads();
  }

  float wgt = (ti == tj) ? 1.f : 2.f;
  float invC[4];
#pragma unroll
  for (int n = 0; n < 4; n++) invC[n] = inv[J0 + wc * 64 + n * 16 + rm];
  float psum = 0.f;
#pragma unroll
  for (int m = 0; m < 4; m++) {
#pragma unroll
    for (int r = 0; r < 4; r++) {
      float invR = inv[I0 + wr * 64 + m * 16 + kq * 4 + r];
#pragma unroll
      for (int n = 0; n < 4; n++) psum += fmaxf(accf[m][n][r] * invR * invC[n], 0.f);
    }
  }
  psum *= wgt;
  for (int off = 32; off; off >>= 1) psum += __shfl_down(psum, off, 64);
  float* r4 = (float*)smem;   // overlays dead lA (k-loop ended with a barrier)
  if (lane == 0) r4[wave] = psum;
  __syncthreads();
  if (tid == 0) pgemm[bx] = r4[0] + r4[1] + r4[2] + r4[3];
}

// ---------------------------------------------------------------------------
// STAGE 4: final reduction over all partial arrays -> out[0].
// ---------------------------------------------------------------------------
__global__ __launch_bounds__(256) void finalize_kernel(const float* __restrict__ psoft,
                                                       const float* __restrict__ pcorn,
                                                       const float* __restrict__ pgemm,
                                                       float* __restrict__ out) {
  __shared__ float r4[4];
  float bce = 0.f;
  for (int i = threadIdx.x; i < 576; i += 256) bce += psoft[i];
  if (threadIdx.x < 16) bce -= pcorn[threadIdx.x];
  float g = 0.f;
  for (int i = threadIdx.x; i < 2176; i += 256) g += pgemm[i];
  float t = bce * (1.f / 2359296.f) + g * (1.f / 67108864.f);
  for (int off = 32; off; off >>= 1) t += __shfl_down(t, off, 64);
  if ((threadIdx.x & 63) == 0) r4[threadIdx.x >> 6] = t;
  __syncthreads();
  if (threadIdx.x == 0) out[0] = r4[0] + r4[1] + r4[2] + r4[3];
}

extern "C" void kernel_launch(void* const* d_in, const int* in_sizes, int n_in,
                              void* d_out, int out_size, void* d_ws, size_t ws_size,
                              hipStream_t stream) {
  (void)in_sizes; (void)n_in; (void)out_size; (void)ws_size;
  const float* desc = (const float*)d_in[0];
  const float* sd = (const float*)d_in[2];
  const float* imgs = (const float*)d_in[3];
  float* out = (float*)d_out;

  char* w = (char*)d_ws;
  float* resp = (float*)(w + OFF_RESP);
  float* cval = (float*)(w + OFF_CVAL);
  unsigned* cpos = (unsigned*)(w + OFF_CPOS);
  unsigned char* descF8 = (unsigned char*)(w + OFF_DESCB);
  float* invn = (float*)(w + OFF_INV);
  float* psoft = (float*)(w + OFF_PSOFT);
  float* pgemm = (float*)(w + OFF_PGEMM);
  float* pcorn = (float*)(w + OFF_PCORN);

  stage1_kernel<<<10496, 256, 0, stream>>>(imgs, resp, desc, descF8, invn);
  stage2_kernel<<<1152, 256, 0, stream>>>(resp, cval, cpos);
  stage3_kernel<<<2768, 256, 0, stream>>>(cval, cpos, sd, pcorn, descF8, invn, pgemm, psoft);
  finalize_kernel<<<1, 256, 0, stream>>>(psoft, pcorn, pgemm, out);
}

// Round 12
// 154.376 us; speedup vs baseline: 1.0307x; 1.0108x over previous
//
#include <hip/hip_runtime.h>

#define H 384
#define W 384
#define HWSZ (H * W)
#define NB 16
#define ND 2048
#define DD 256

// workspace byte offsets (all 256-aligned)
#define OFF_RESP  256
#define OFF_CVAL  9437440
#define OFF_CPOS  9584896
#define OFF_DESCB 9732352     // fp8 descriptors: 16*2048*256 = 8.4 MB
#define OFF_INV   26509568
#define OFF_PSOFT 26640640    // 576 floats
#define OFF_PGEMM 26643200    // 2176 floats
#define OFF_PCORN 26652160    // 16 floats

__device__ __forceinline__ int clampi(int v) { return v < 0 ? 0 : (v > 383 ? 383 : v); }
__device__ __forceinline__ int refl(int v) { return v < 0 ? -v : (v >= 384 ? 766 - v : v); }

// fp32 -> OCP e4m3fn with RNE. Layout: [s:1][eeee:4][mmm:3] -> s<<7 | e<<3 | m.
__device__ __forceinline__ unsigned f2e4m3(float x) {
  float a = fabsf(x);
  unsigned s = (__float_as_uint(x) >> 31) << 7;
  if (a >= 448.f) return s | 0x7E;
  if (a < 0.015625f) {
    int m = (int)rintf(a * 512.f);
    return s | (unsigned)m;
  }
  unsigned u = __float_as_uint(a);
  u += 0x7FFFF + ((u >> 20) & 1);
  unsigned e = (u >> 23) - 120;
  unsigned m = (u >> 20) & 7;
  return s | (e << 3) | m;
}

typedef float f32x4 __attribute__((ext_vector_type(4)));

__device__ __forceinline__ void load_lds16(const void* g, void* l) {
  __builtin_amdgcn_global_load_lds((const __attribute__((address_space(1))) void*)g,
                                   (__attribute__((address_space(3))) void*)l, 16, 0, 0);
}

// ---------------------------------------------------------------------------
// STAGE 1: resp (blocks 0..2303) || prep_desc (blocks 2304..10495).
// ---------------------------------------------------------------------------
__global__ __launch_bounds__(256) void stage1_kernel(const float* __restrict__ imgs,
                                                     float* __restrict__ resp,
                                                     const float* __restrict__ desc,
                                                     unsigned char* __restrict__ descF8,
                                                     float* __restrict__ invn) {
  __shared__ float pbuf[4448];   // p0/p1/p2: 3 x [38][39]
  __shared__ float ubuf[3648];   // union: gl[40][41] (phases 0-1) / t0..t2 [38][32] (2-3)
  float* p0 = pbuf;
  float* p1 = pbuf + 1482;
  float* p2 = pbuf + 2964;
  float* glf = ubuf;             // stride 41
  float* t0 = ubuf;              // stride 32
  float* t1 = ubuf + 1216;
  float* t2 = ubuf + 2432;

  if (blockIdx.x >= 2304) {
    // ---- prep_desc: fp32 -> fp8 e4m3 + per-row inverse norm ----
    int wave = threadIdx.x >> 6, lane = threadIdx.x & 63;
    int row = (blockIdx.x - 2304) * 4 + wave;
    const float4* src = (const float4*)(desc + (size_t)row * DD);
    float4 v = src[lane];
    unsigned pk = f2e4m3(v.x) | (f2e4m3(v.y) << 8) | (f2e4m3(v.z) << 16) | (f2e4m3(v.w) << 24);
    ((unsigned*)(descF8 + (size_t)row * DD))[lane] = pk;
    float ss = v.x * v.x + v.y * v.y + v.z * v.z + v.w * v.w;
    for (int off = 32; off; off >>= 1) ss += __shfl_down(ss, off, 64);
    if (lane == 0) invn[row] = 1.f / fmaxf(sqrtf(ss), 1e-4f);
    return;
  }

  // ---- resp: gray -> sobel(edge) -> products -> 7x7 gauss(reflect) -> GFTT ----
  const float GW[7] = {0.0044330482f, 0.0540055826f, 0.2420362294f, 0.3990502160f,
                       0.2420362294f, 0.0540055826f, 0.0044330482f};
  int bid = blockIdx.x;
  int b = bid / 144;
  int t = bid % 144;
  int Y0 = (t / 12) * 32, X0 = (t % 12) * 32;
  const float* ib = imgs + (size_t)b * 3 * HWSZ;

  for (int i = threadIdx.x; i < 1600; i += 256) {
    int r = i / 40, c = i % 40;
    int gy = clampi(Y0 - 4 + r), gx = clampi(X0 - 4 + c);
    const float* p = ib + gy * W + gx;
    glf[r * 41 + c] = 0.299f * p[0] + 0.587f * p[HWSZ] + 0.114f * p[2 * HWSZ];
  }
  __syncthreads();

  bool interior = (X0 >= 32 && X0 <= 320 && Y0 >= 32 && Y0 <= 320);

  if (interior) {
    for (int i = threadIdx.x; i < 1444; i += 256) {
      int r = i / 38, c = i % 38;
      const float* g0 = glf + r * 41 + c;
      float a = g0[0],  bb = g0[1],  cc = g0[2];
      float d = g0[41],              e = g0[43];
      float f = g0[82], g = g0[83],  h = g0[84];
      float dx = 0.125f * ((cc - a) + 2.f * (e - d) + (h - f));
      float dy = 0.125f * ((f - a) + 2.f * (g - bb) + (h - cc));
      p0[r * 39 + c] = dx * dx;
      p1[r * 39 + c] = dy * dy;
      p2[r * 39 + c] = dx * dy;
    }
  } else {
    for (int i = threadIdx.x; i < 1444; i += 256) {
      int r = i / 38, c = i % 38;
      int py = refl(Y0 - 3 + r), px = refl(X0 - 3 + c);
      int ym = clampi(py - 1) - (Y0 - 4), y0 = py - (Y0 - 4), yp = clampi(py + 1) - (Y0 - 4);
      int xm = clampi(px - 1) - (X0 - 4), x0 = px - (X0 - 4), xp = clampi(px + 1) - (X0 - 4);
      float a = glf[ym * 41 + xm], bb = glf[ym * 41 + x0], cc = glf[ym * 41 + xp];
      float d = glf[y0 * 41 + xm], e = glf[y0 * 41 + xp];
      float f = glf[yp * 41 + xm], g = glf[yp * 41 + x0], h = glf[yp * 41 + xp];
      float dx = 0.125f * ((cc - a) + 2.f * (e - d) + (h - f));
      float dy = 0.125f * ((f - a) + 2.f * (g - bb) + (h - cc));
      p0[r * 39 + c] = dx * dx;
      p1[r * 39 + c] = dy * dy;
      p2[r * 39 + c] = dx * dy;
    }
  }
  __syncthreads();

  for (int g = threadIdx.x; g < 304; g += 256) {
    int r = g >> 3, c0 = (g & 7) * 4;
    {
      float a[10];
#pragma unroll
      for (int dc = 0; dc < 10; dc++) a[dc] = p0[r * 39 + c0 + dc];
#pragma unroll
      for (int k = 0; k < 4; k++) {
        float sv = 0.f;
#pragma unroll
        for (int j = 0; j < 7; j++) sv += GW[j] * a[k + j];
        t0[r * 32 + c0 + k] = sv;
      }
    }
    {
      float a[10];
#pragma unroll
      for (int dc = 0; dc < 10; dc++) a[dc] = p1[r * 39 + c0 + dc];
#pragma unroll
      for (int k = 0; k < 4; k++) {
        float sv = 0.f;
#pragma unroll
        for (int j = 0; j < 7; j++) sv += GW[j] * a[k + j];
        t1[r * 32 + c0 + k] = sv;
      }
    }
    {
      float a[10];
#pragma unroll
      for (int dc = 0; dc < 10; dc++) a[dc] = p2[r * 39 + c0 + dc];
#pragma unroll
      for (int k = 0; k < 4; k++) {
        float sv = 0.f;
#pragma unroll
        for (int j = 0; j < 7; j++) sv += GW[j] * a[k + j];
        t2[r * 32 + c0 + k] = sv;
      }
    }
  }
  __syncthreads();

  {
    int r0 = (threadIdx.x >> 5) * 4, c = threadIdx.x & 31;
    float s0[4], s1[4], s2[4];
    {
      float a[10];
#pragma unroll
      for (int dr = 0; dr < 10; dr++) a[dr] = t0[(r0 + dr) * 32 + c];
#pragma unroll
      for (int k = 0; k < 4; k++) {
        float sv = 0.f;
#pragma unroll
        for (int j = 0; j < 7; j++) sv += GW[j] * a[k + j];
        s0[k] = sv;
      }
    }
    {
      float a[10];
#pragma unroll
      for (int dr = 0; dr < 10; dr++) a[dr] = t1[(r0 + dr) * 32 + c];
#pragma unroll
      for (int k = 0; k < 4; k++) {
        float sv = 0.f;
#pragma unroll
        for (int j = 0; j < 7; j++) sv += GW[j] * a[k + j];
        s1[k] = sv;
      }
    }
    {
      float a[10];
#pragma unroll
      for (int dr = 0; dr < 10; dr++) a[dr] = t2[(r0 + dr) * 32 + c];
#pragma unroll
      for (int k = 0; k < 4; k++) {
        float sv = 0.f;
#pragma unroll
        for (int j = 0; j < 7; j++) sv += GW[j] * a[k + j];
        s2[k] = sv;
      }
    }
#pragma unroll
    for (int k = 0; k < 4; k++) {
      float tr = s0[k] + s1[k];
      float det = s0[k] * s1[k] - s2[k] * s2[k];
      float disc = tr * tr - 4.f * det;
      float rv = 0.5f * (tr - sqrtf(fabsf(disc)));
      resp[(size_t)b * HWSZ + (Y0 + r0 + k) * W + (X0 + c)] = rv;
    }
  }
}

// ---------------------------------------------------------------------------
// STAGE 2: nms 64x32 tiles (blocks 0..1151) || softplus (1152..1727).
// NOTE: grid MUST be 1728 (1152 nms + 576 softplus) — R11 failed because
// it launched only 1152 blocks, leaving psoft unwritten (poison).
// ---------------------------------------------------------------------------
__global__ __launch_bounds__(256) void stage2_kernel(const float* __restrict__ resp,
                                                     float* __restrict__ cval,
                                                     unsigned* __restrict__ cpos,
                                                     const float4* __restrict__ sd4,
                                                     float* __restrict__ psoft) {
  __shared__ float rl[68][37];    // 10064 B
  __shared__ float rmx[68][32];   // 8704 B
  __shared__ float r4[4];

  if (blockIdx.x >= 1152) {
    // ---- softplus partial sums ----
    int sb = blockIdx.x - 1152;
    float s = 0.f;
    int base = sb * 256 + threadIdx.x;
#pragma unroll
    for (int it = 0; it < 4; it++) {
      float4 v = sd4[base + it * 147456];
      s += fmaxf(v.x, 0.f) + log1pf(expf(-fabsf(v.x))) +
           fmaxf(v.y, 0.f) + log1pf(expf(-fabsf(v.y))) +
           fmaxf(v.z, 0.f) + log1pf(expf(-fabsf(v.z))) +
           fmaxf(v.w, 0.f) + log1pf(expf(-fabsf(v.w)));
    }
    for (int off = 32; off; off >>= 1) s += __shfl_down(s, off, 64);
    if ((threadIdx.x & 63) == 0) r4[threadIdx.x >> 6] = s;
    __syncthreads();
    if (threadIdx.x == 0) psoft[sb] = r4[0] + r4[1] + r4[2] + r4[3];
    return;
  }

  // ---- 5x5 NMS, 64x32 tile (-inf border), separable max ----
  int bid = blockIdx.x;
  int b = bid / 72;
  int t = bid % 72;
  int Y0 = (t / 12) * 64, X0 = (t % 12) * 32;
  const float* rb = resp + (size_t)b * HWSZ;

  for (int i = threadIdx.x; i < 68 * 36; i += 256) {
    int r = i / 36, c = i % 36;
    int gy = Y0 - 2 + r, gx = X0 - 2 + c;
    float v = -INFINITY;
    if (gy >= 0 && gy < H && gx >= 0 && gx < W) v = rb[gy * W + gx];
    rl[r][c] = v;
  }
  __syncthreads();

  // horizontal 5-max: 68 rows x 32 output cols
  for (int i = threadIdx.x; i < 68 * 32; i += 256) {
    int r = i / 32, c = i % 32;
    float m = rl[r][c];
    m = fmaxf(m, rl[r][c + 1]);
    m = fmaxf(m, rl[r][c + 2]);
    m = fmaxf(m, rl[r][c + 3]);
    m = fmaxf(m, rl[r][c + 4]);
    rmx[r][c] = m;
  }
  __syncthreads();

  // vertical 5-max + nms verdict written in place into rl's center
  for (int i = threadIdx.x; i < 2048; i += 256) {
    int r = i / 32, c = i % 32;
    float m = rmx[r][c];
    m = fmaxf(m, rmx[r + 1][c]);
    m = fmaxf(m, rmx[r + 2][c]);
    m = fmaxf(m, rmx[r + 3][c]);
    m = fmaxf(m, rmx[r + 4][c]);
    float v = rl[r + 2][c + 2];
    rl[r + 2][c + 2] = (v == m) ? v : 0.f;
  }
  __syncthreads();

  if (threadIdx.x < 32) {
    int bi = threadIdx.x >> 2, bj = threadIdx.x & 3;   // 8x4 sub-blocks of 8x8
    float bv = 0.f;
    unsigned bp = 0;
    for (int rr = 0; rr < 8; rr++)
      for (int cc = 0; cc < 8; cc++) {
        float v = rl[bi * 8 + rr + 2][bj * 8 + cc + 2];
        if (v > bv) { bv = v; bp = (unsigned)((Y0 + bi * 8 + rr) * W + (X0 + bj * 8 + cc)); }
      }
    int ci = b * 2304 + (Y0 / 8 + bi) * 48 + (X0 / 8 + bj);
    cval[ci] = bv;
    cpos[ci] = bp;
  }
}

// ---------------------------------------------------------------------------
// STAGE 3: topk radix-select (blocks 0..15, hides under gemm) || fp8
// Gram-GEMM relu-sum (16..2191), swizzled LDS + XCD-chunked order.
// One 32768-byte LDS union -> 5 blocks/CU.
// ---------------------------------------------------------------------------
__global__ __launch_bounds__(256) void stage3_kernel(const float* __restrict__ cval,
                                                     const unsigned* __restrict__ cpos,
                                                     const float* __restrict__ sd,
                                                     float* __restrict__ pcorn,
                                                     const unsigned char* __restrict__ descF8,
                                                     const float* __restrict__ invn,
                                                     float* __restrict__ pgemm) {
  alignas(16) __shared__ char smem[32768];
  int tid = threadIdx.x;

  if (blockIdx.x < 16) {
    // ---- topk radix-select for batch b ----
    int* hist = (int*)smem;                      // 1024 B
    int* pick = (int*)(smem + 1024);             // 8 B
    int* eqcnt = (int*)(smem + 1032);            // 4 B
    int* ri = (int*)(smem + 1040);               // 16 B
    unsigned* eqpos = (unsigned*)(smem + 1056);  // 1024 B
    float* r4 = (float*)(smem + 2080);           // 16 B

    int b = blockIdx.x;
    int t = tid;
    int lane = t & 63;

    unsigned bits[9], pos[9];
#pragma unroll
    for (int q = 0; q < 9; q++) {
      int i = t + q * 256;
      unsigned vb = 0, p = 0;
      if (i < 2304) {
        float v = cval[b * 2304 + i];
        if (v > 0.f) { vb = __float_as_uint(v); p = cpos[b * 2304 + i]; }
      }
      bits[q] = vb; pos[q] = p;
    }

    int P = 0;
#pragma unroll
    for (int q = 0; q < 9; q++) P += (bits[q] != 0u);
    for (int off = 32; off; off >>= 1) P += __shfl_down(P, off, 64);
    if (lane == 0) ri[t >> 6] = P;
    __syncthreads();
    int Ptot = ri[0] + ri[1] + ri[2] + ri[3];
    if (Ptot == 0) { if (t == 0) pcorn[b] = 0.f; return; }
    int K = Ptot < 200 ? Ptot : 200;

    unsigned prefix = 0;
    int krem = K;
    for (int shift = 24; shift >= 0; shift -= 8) {
      hist[t] = 0;
      __syncthreads();
#pragma unroll
      for (int q = 0; q < 9; q++) {
        if (bits[q] != 0u &&
            (shift == 24 || (bits[q] >> (shift + 8)) == (prefix >> (shift + 8))))
          atomicAdd(&hist[(bits[q] >> shift) & 0xFF], 1);
      }
      __syncthreads();
      if (t < 64) {
        int h0 = hist[4 * t], h1 = hist[4 * t + 1], h2 = hist[4 * t + 2], h3 = hist[4 * t + 3];
        int tot = h0 + h1 + h2 + h3;
        int acc = tot;
        for (int d = 1; d < 64; d <<= 1) {
          int o = __shfl_down(acc, d, 64);
          if (t + d < 64) acc += o;
        }
        int excl = acc - tot;
        int G3 = excl, G2 = excl + h3, G1 = excl + h3 + h2, G0 = excl + h3 + h2 + h1;
        if (G0 < krem && G0 + h0 >= krem) { pick[0] = 4 * t;     pick[1] = G0; }
        if (G1 < krem && G1 + h1 >= krem) { pick[0] = 4 * t + 1; pick[1] = G1; }
        if (G2 < krem && G2 + h2 >= krem) { pick[0] = 4 * t + 2; pick[1] = G2; }
        if (G3 < krem && G3 + h3 >= krem) { pick[0] = 4 * t + 3; pick[1] = G3; }
      }
      __syncthreads();
      prefix |= ((unsigned)pick[0]) << shift;
      krem -= pick[1];
      __syncthreads();
    }

    if (t == 0) *eqcnt = 0;
    __syncthreads();
    float s = 0.f;
#pragma unroll
    for (int q = 0; q < 9; q++) {
      if (bits[q] > prefix) s += sd[(size_t)b * HWSZ + pos[q]];
      else if (bits[q] != 0u && bits[q] == prefix) {
        int idx = atomicAdd(eqcnt, 1);
        if (idx < 256) eqpos[idx] = pos[q];
      }
    }
    __syncthreads();
    int m = *eqcnt;
    if (m <= krem) {
      if (t < m) s += sd[(size_t)b * HWSZ + eqpos[t]];
    } else {
      int mm = m < 256 ? m : 256;
      if (t < mm) {
        unsigned p = eqpos[t];
        int rank = 0;
        for (int u = 0; u < mm; u++) rank += (eqpos[u] < p);
        if (rank < krem) s += sd[(size_t)b * HWSZ + p];
      }
    }
    for (int off = 32; off; off >>= 1) s += __shfl_down(s, off, 64);
    if (lane == 0) r4[t >> 6] = s;
    __syncthreads();
    if (t == 0) pcorn[b] = r4[0] + r4[1] + r4[2] + r4[3];
    return;
  }

  // ---- fp8 Gram-GEMM with relu-sum epilogue; swizzled LDS ----
  char* lA = smem;
  char* lB = smem + 16384;

  int bxl = blockIdx.x - 16;                // 0..2175; 16%8==0 keeps XCD map
  int bx = ((bxl & 7) * 272) + (bxl >> 3);  // contiguous 272-chunk per XCD
  int batch = bx / 136;
  int rem = bx % 136;
  int ti = 0, rowlen = 16;
  while (rem >= rowlen) { rem -= rowlen; rowlen--; ti++; }
  int tj = ti + rem;

  const unsigned char* Ab = descF8 + (size_t)batch * ND * DD;
  const float* inv = invn + batch * ND;
  int I0 = ti * 128, J0 = tj * 128;

  int wave = tid >> 6, lane = tid & 63;
  int rm = lane & 15, kq = lane >> 4;
  int wr = wave >> 1, wc = wave & 1;
  int lrow = lane >> 3;
  int lcolb = ((lane & 7) ^ lrow) << 4;   // swizzled source column (bytes)
  int cx = rm & 7;                        // read-side swizzle key

  f32x4 accf[4][4];
#pragma unroll
  for (int m = 0; m < 4; m++)
#pragma unroll
    for (int n = 0; n < 4; n++) accf[m][n] = (f32x4){0.f, 0.f, 0.f, 0.f};

  for (int k0 = 0; k0 < DD; k0 += 128) {
#pragma unroll
    for (int q = 0; q < 4; q++) {
      int chunk = wave * 4 + q;
      load_lds16(Ab + (size_t)(I0 + chunk * 8 + lrow) * DD + k0 + lcolb, lA + chunk * 1024);
      load_lds16(Ab + (size_t)(J0 + chunk * 8 + lrow) * DD + k0 + lcolb, lB + chunk * 1024);
    }
    __syncthreads();
#pragma unroll
    for (int kk = 0; kk < 128; kk += 32) {
      long af[4], bfr[4];
      int koff = kk + kq * 8;
      int pcol = ((((koff >> 4) ^ cx) << 4) | (koff & 8));
#pragma unroll
      for (int m = 0; m < 4; m++)
        af[m] = *reinterpret_cast<const long*>(lA + (wr * 64 + m * 16 + rm) * 128 + pcol);
#pragma unroll
      for (int n = 0; n < 4; n++)
        bfr[n] = *reinterpret_cast<const long*>(lB + (wc * 64 + n * 16 + rm) * 128 + pcol);
#pragma unroll
      for (int m = 0; m < 4; m++)
#pragma unroll
        for (int n = 0; n < 4; n++)
          accf[m][n] = __builtin_amdgcn_mfma_f32_16x16x32_fp8_fp8(af[m], bfr[n], accf[m][n], 0, 0, 0);
    }
    __syncthreads();
  }

  float wgt = (ti == tj) ? 1.f : 2.f;
  float invC[4];
#pragma unroll
  for (int n = 0; n < 4; n++) invC[n] = inv[J0 + wc * 64 + n * 16 + rm];
  float psum = 0.f;
#pragma unroll
  for (int m = 0; m < 4; m++) {
#pragma unroll
    for (int r = 0; r < 4; r++) {
      float invR = inv[I0 + wr * 64 + m * 16 + kq * 4 + r];
#pragma unroll
      for (int n = 0; n < 4; n++) psum += fmaxf(accf[m][n][r] * invR * invC[n], 0.f);
    }
  }
  psum *= wgt;
  for (int off = 32; off; off >>= 1) psum += __shfl_down(psum, off, 64);
  float* r4 = (float*)smem;   // overlays dead lA (k-loop ended with a barrier)
  if (lane == 0) r4[wave] = psum;
  __syncthreads();
  if (tid == 0) pgemm[bx] = r4[0] + r4[1] + r4[2] + r4[3];
}

// ---------------------------------------------------------------------------
// STAGE 4: final reduction over all partial arrays -> out[0].
// ---------------------------------------------------------------------------
__global__ __launch_bounds__(256) void finalize_kernel(const float* __restrict__ psoft,
                                                       const float* __restrict__ pcorn,
                                                       const float* __restrict__ pgemm,
                                                       float* __restrict__ out) {
  __shared__ float r4[4];
  float bce = 0.f;
  for (int i = threadIdx.x; i < 576; i += 256) bce += psoft[i];
  if (threadIdx.x < 16) bce -= pcorn[threadIdx.x];
  float g = 0.f;
  for (int i = threadIdx.x; i < 2176; i += 256) g += pgemm[i];
  float t = bce * (1.f / 2359296.f) + g * (1.f / 67108864.f);
  for (int off = 32; off; off >>= 1) t += __shfl_down(t, off, 64);
  if ((threadIdx.x & 63) == 0) r4[threadIdx.x >> 6] = t;
  __syncthreads();
  if (threadIdx.x == 0) out[0] = r4[0] + r4[1] + r4[2] + r4[3];
}

extern "C" void kernel_launch(void* const* d_in, const int* in_sizes, int n_in,
                              void* d_out, int out_size, void* d_ws, size_t ws_size,
                              hipStream_t stream) {
  (void)in_sizes; (void)n_in; (void)out_size; (void)ws_size;
  const float* desc = (const float*)d_in[0];
  const float* sd = (const float*)d_in[2];
  const float* imgs = (const float*)d_in[3];
  float* out = (float*)d_out;

  char* w = (char*)d_ws;
  float* resp = (float*)(w + OFF_RESP);
  float* cval = (float*)(w + OFF_CVAL);
  unsigned* cpos = (unsigned*)(w + OFF_CPOS);
  unsigned char* descF8 = (unsigned char*)(w + OFF_DESCB);
  float* invn = (float*)(w + OFF_INV);
  float* psoft = (float*)(w + OFF_PSOFT);
  float* pgemm = (float*)(w + OFF_PGEMM);
  float* pcorn = (float*)(w + OFF_PCORN);

  stage1_kernel<<<10496, 256, 0, stream>>>(imgs, resp, desc, descF8, invn);
  stage2_kernel<<<1728, 256, 0, stream>>>(resp, cval, cpos, (const float4*)sd, psoft);
  stage3_kernel<<<2192, 256, 0, stream>>>(cval, cpos, sd, pcorn, descF8, invn, pgemm);
  finalize_kernel<<<1, 256, 0, stream>>>(psoft, pcorn, pgemm, out);
}

// Round 13
// 150.841 us; speedup vs baseline: 1.0549x; 1.0234x over previous
//
#include <hip/hip_runtime.h>

#define H 384
#define W 384
#define HWSZ (H * W)
#define NB 16
#define ND 2048
#define DD 256

// workspace byte offsets (all 256-aligned)
#define OFF_RESP  256
#define OFF_CVAL  9437440
#define OFF_CPOS  9584896
#define OFF_DESCB 9732352     // fp8 descriptors: 16*2048*256 = 8.4 MB
#define OFF_INV   26509568
#define OFF_PSOFT 26640640    // 576 floats
#define OFF_PGEMM 26643200    // 2176 floats
#define OFF_PCORN 26652160    // 16 floats

__device__ __forceinline__ int clampi(int v) { return v < 0 ? 0 : (v > 383 ? 383 : v); }
__device__ __forceinline__ int refl(int v) { return v < 0 ? -v : (v >= 384 ? 766 - v : v); }

// fp32 -> OCP e4m3fn with RNE. Layout: [s:1][eeee:4][mmm:3] -> s<<7 | e<<3 | m.
__device__ __forceinline__ unsigned f2e4m3(float x) {
  float a = fabsf(x);
  unsigned s = (__float_as_uint(x) >> 31) << 7;
  if (a >= 448.f) return s | 0x7E;
  if (a < 0.015625f) {
    int m = (int)rintf(a * 512.f);
    return s | (unsigned)m;
  }
  unsigned u = __float_as_uint(a);
  u += 0x7FFFF + ((u >> 20) & 1);
  unsigned e = (u >> 23) - 120;
  unsigned m = (u >> 20) & 7;
  return s | (e << 3) | m;
}

typedef float f32x4 __attribute__((ext_vector_type(4)));

__device__ __forceinline__ void load_lds16(const void* g, void* l) {
  __builtin_amdgcn_global_load_lds((const __attribute__((address_space(1))) void*)g,
                                   (__attribute__((address_space(3))) void*)l, 16, 0, 0);
}

// ---------------------------------------------------------------------------
// STAGE 1: resp (blocks 0..2303) || prep_desc (blocks 2304..10495).
// vs R6/R12: store dx,dy in LDS (2 arrays) instead of dx2,dy2,dxdy (3);
// products formed in-register inside the horizontal gauss. Same fp32 ops
// in the same order -> bitwise identical. LDS 32,384 -> 26,448 B
// (6 blocks/CU instead of 5), minus one LDS write pass.
// ---------------------------------------------------------------------------
__global__ __launch_bounds__(256) void stage1_kernel(const float* __restrict__ imgs,
                                                     float* __restrict__ resp,
                                                     const float* __restrict__ desc,
                                                     unsigned char* __restrict__ descF8,
                                                     float* __restrict__ invn) {
  __shared__ float pbuf[2964];   // pd/pe: 2 x [38][39] (dx, dy)
  __shared__ float ubuf[3648];   // union: gl[40][41] (phases 0-1) / t0..t2 [38][32] (2-3)
  float* pd = pbuf;
  float* pe = pbuf + 1482;
  float* glf = ubuf;             // stride 41
  float* t0 = ubuf;              // stride 32
  float* t1 = ubuf + 1216;
  float* t2 = ubuf + 2432;

  if (blockIdx.x >= 2304) {
    // ---- prep_desc: fp32 -> fp8 e4m3 + per-row inverse norm ----
    int wave = threadIdx.x >> 6, lane = threadIdx.x & 63;
    int row = (blockIdx.x - 2304) * 4 + wave;
    const float4* src = (const float4*)(desc + (size_t)row * DD);
    float4 v = src[lane];
    unsigned pk = f2e4m3(v.x) | (f2e4m3(v.y) << 8) | (f2e4m3(v.z) << 16) | (f2e4m3(v.w) << 24);
    ((unsigned*)(descF8 + (size_t)row * DD))[lane] = pk;
    float ss = v.x * v.x + v.y * v.y + v.z * v.z + v.w * v.w;
    for (int off = 32; off; off >>= 1) ss += __shfl_down(ss, off, 64);
    if (lane == 0) invn[row] = 1.f / fmaxf(sqrtf(ss), 1e-4f);
    return;
  }

  // ---- resp: gray -> sobel(edge) -> 7x7 gauss(reflect) of products -> GFTT ----
  const float GW[7] = {0.0044330482f, 0.0540055826f, 0.2420362294f, 0.3990502160f,
                       0.2420362294f, 0.0540055826f, 0.0044330482f};
  int bid = blockIdx.x;
  int b = bid / 144;
  int t = bid % 144;
  int Y0 = (t / 12) * 32, X0 = (t % 12) * 32;
  const float* ib = imgs + (size_t)b * 3 * HWSZ;

  for (int i = threadIdx.x; i < 1600; i += 256) {
    int r = i / 40, c = i % 40;
    int gy = clampi(Y0 - 4 + r), gx = clampi(X0 - 4 + c);
    const float* p = ib + gy * W + gx;
    glf[r * 41 + c] = 0.299f * p[0] + 0.587f * p[HWSZ] + 0.114f * p[2 * HWSZ];
  }
  __syncthreads();

  bool interior = (X0 >= 32 && X0 <= 320 && Y0 >= 32 && Y0 <= 320);

  if (interior) {
    for (int i = threadIdx.x; i < 1444; i += 256) {
      int r = i / 38, c = i % 38;
      const float* g0 = glf + r * 41 + c;
      float a = g0[0],  bb = g0[1],  cc = g0[2];
      float d = g0[41],              e = g0[43];
      float f = g0[82], g = g0[83],  h = g0[84];
      float dx = 0.125f * ((cc - a) + 2.f * (e - d) + (h - f));
      float dy = 0.125f * ((f - a) + 2.f * (g - bb) + (h - cc));
      pd[r * 39 + c] = dx;
      pe[r * 39 + c] = dy;
    }
  } else {
    for (int i = threadIdx.x; i < 1444; i += 256) {
      int r = i / 38, c = i % 38;
      int py = refl(Y0 - 3 + r), px = refl(X0 - 3 + c);
      int ym = clampi(py - 1) - (Y0 - 4), y0 = py - (Y0 - 4), yp = clampi(py + 1) - (Y0 - 4);
      int xm = clampi(px - 1) - (X0 - 4), x0 = px - (X0 - 4), xp = clampi(px + 1) - (X0 - 4);
      float a = glf[ym * 41 + xm], bb = glf[ym * 41 + x0], cc = glf[ym * 41 + xp];
      float d = glf[y0 * 41 + xm], e = glf[y0 * 41 + xp];
      float f = glf[yp * 41 + xm], g = glf[yp * 41 + x0], h = glf[yp * 41 + xp];
      float dx = 0.125f * ((cc - a) + 2.f * (e - d) + (h - f));
      float dy = 0.125f * ((f - a) + 2.f * (g - bb) + (h - cc));
      pd[r * 39 + c] = dx;
      pe[r * 39 + c] = dy;
    }
  }
  __syncthreads();

  // horizontal gauss over products (products formed in-register from dx,dy;
  // identical fp32 multiply + identical j-ascending sum -> bitwise same).
  for (int g = threadIdx.x; g < 304; g += 256) {
    int r = g >> 3, c0 = (g & 7) * 4;
    float d[10], e[10];
#pragma unroll
    for (int dc = 0; dc < 10; dc++) {
      d[dc] = pd[r * 39 + c0 + dc];
      e[dc] = pe[r * 39 + c0 + dc];
    }
#pragma unroll
    for (int k = 0; k < 4; k++) {
      float sv = 0.f;
#pragma unroll
      for (int j = 0; j < 7; j++) sv += GW[j] * (d[k + j] * d[k + j]);
      t0[r * 32 + c0 + k] = sv;
    }
#pragma unroll
    for (int k = 0; k < 4; k++) {
      float sv = 0.f;
#pragma unroll
      for (int j = 0; j < 7; j++) sv += GW[j] * (e[k + j] * e[k + j]);
      t1[r * 32 + c0 + k] = sv;
    }
#pragma unroll
    for (int k = 0; k < 4; k++) {
      float sv = 0.f;
#pragma unroll
      for (int j = 0; j < 7; j++) sv += GW[j] * (d[k + j] * e[k + j]);
      t2[r * 32 + c0 + k] = sv;
    }
  }
  __syncthreads();

  // vertical gauss + GFTT: 4 rows/thread via 10-deep sliding window
  {
    int r0 = (threadIdx.x >> 5) * 4, c = threadIdx.x & 31;
    float s0[4], s1[4], s2[4];
    {
      float a[10];
#pragma unroll
      for (int dr = 0; dr < 10; dr++) a[dr] = t0[(r0 + dr) * 32 + c];
#pragma unroll
      for (int k = 0; k < 4; k++) {
        float sv = 0.f;
#pragma unroll
        for (int j = 0; j < 7; j++) sv += GW[j] * a[k + j];
        s0[k] = sv;
      }
    }
    {
      float a[10];
#pragma unroll
      for (int dr = 0; dr < 10; dr++) a[dr] = t1[(r0 + dr) * 32 + c];
#pragma unroll
      for (int k = 0; k < 4; k++) {
        float sv = 0.f;
#pragma unroll
        for (int j = 0; j < 7; j++) sv += GW[j] * a[k + j];
        s1[k] = sv;
      }
    }
    {
      float a[10];
#pragma unroll
      for (int dr = 0; dr < 10; dr++) a[dr] = t2[(r0 + dr) * 32 + c];
#pragma unroll
      for (int k = 0; k < 4; k++) {
        float sv = 0.f;
#pragma unroll
        for (int j = 0; j < 7; j++) sv += GW[j] * a[k + j];
        s2[k] = sv;
      }
    }
#pragma unroll
    for (int k = 0; k < 4; k++) {
      float tr = s0[k] + s1[k];
      float det = s0[k] * s1[k] - s2[k] * s2[k];
      float disc = tr * tr - 4.f * det;
      float rv = 0.5f * (tr - sqrtf(fabsf(disc)));
      resp[(size_t)b * HWSZ + (Y0 + r0 + k) * W + (X0 + c)] = rv;
    }
  }
}

// ---------------------------------------------------------------------------
// STAGE 2: nms 64x32 tiles (blocks 0..1151) || softplus (1152..1727).
// Grid MUST be 1728 (1152 nms + 576 softplus).
// ---------------------------------------------------------------------------
__global__ __launch_bounds__(256) void stage2_kernel(const float* __restrict__ resp,
                                                     float* __restrict__ cval,
                                                     unsigned* __restrict__ cpos,
                                                     const float4* __restrict__ sd4,
                                                     float* __restrict__ psoft) {
  __shared__ float rl[68][37];    // 10064 B
  __shared__ float rmx[68][32];   // 8704 B
  __shared__ float r4[4];

  if (blockIdx.x >= 1152) {
    // ---- softplus partial sums ----
    int sb = blockIdx.x - 1152;
    float s = 0.f;
    int base = sb * 256 + threadIdx.x;
#pragma unroll
    for (int it = 0; it < 4; it++) {
      float4 v = sd4[base + it * 147456];
      s += fmaxf(v.x, 0.f) + log1pf(expf(-fabsf(v.x))) +
           fmaxf(v.y, 0.f) + log1pf(expf(-fabsf(v.y))) +
           fmaxf(v.z, 0.f) + log1pf(expf(-fabsf(v.z))) +
           fmaxf(v.w, 0.f) + log1pf(expf(-fabsf(v.w)));
    }
    for (int off = 32; off; off >>= 1) s += __shfl_down(s, off, 64);
    if ((threadIdx.x & 63) == 0) r4[threadIdx.x >> 6] = s;
    __syncthreads();
    if (threadIdx.x == 0) psoft[sb] = r4[0] + r4[1] + r4[2] + r4[3];
    return;
  }

  // ---- 5x5 NMS, 64x32 tile (-inf border), separable max ----
  int bid = blockIdx.x;
  int b = bid / 72;
  int t = bid % 72;
  int Y0 = (t / 12) * 64, X0 = (t % 12) * 32;
  const float* rb = resp + (size_t)b * HWSZ;

  for (int i = threadIdx.x; i < 68 * 36; i += 256) {
    int r = i / 36, c = i % 36;
    int gy = Y0 - 2 + r, gx = X0 - 2 + c;
    float v = -INFINITY;
    if (gy >= 0 && gy < H && gx >= 0 && gx < W) v = rb[gy * W + gx];
    rl[r][c] = v;
  }
  __syncthreads();

  // horizontal 5-max: 68 rows x 32 output cols
  for (int i = threadIdx.x; i < 68 * 32; i += 256) {
    int r = i / 32, c = i % 32;
    float m = rl[r][c];
    m = fmaxf(m, rl[r][c + 1]);
    m = fmaxf(m, rl[r][c + 2]);
    m = fmaxf(m, rl[r][c + 3]);
    m = fmaxf(m, rl[r][c + 4]);
    rmx[r][c] = m;
  }
  __syncthreads();

  // vertical 5-max + nms verdict written in place into rl's center
  for (int i = threadIdx.x; i < 2048; i += 256) {
    int r = i / 32, c = i % 32;
    float m = rmx[r][c];
    m = fmaxf(m, rmx[r + 1][c]);
    m = fmaxf(m, rmx[r + 2][c]);
    m = fmaxf(m, rmx[r + 3][c]);
    m = fmaxf(m, rmx[r + 4][c]);
    float v = rl[r + 2][c + 2];
    rl[r + 2][c + 2] = (v == m) ? v : 0.f;
  }
  __syncthreads();

  if (threadIdx.x < 32) {
    int bi = threadIdx.x >> 2, bj = threadIdx.x & 3;   // 8x4 sub-blocks of 8x8
    float bv = 0.f;
    unsigned bp = 0;
    for (int rr = 0; rr < 8; rr++)
      for (int cc = 0; cc < 8; cc++) {
        float v = rl[bi * 8 + rr + 2][bj * 8 + cc + 2];
        if (v > bv) { bv = v; bp = (unsigned)((Y0 + bi * 8 + rr) * W + (X0 + bj * 8 + cc)); }
      }
    int ci = b * 2304 + (Y0 / 8 + bi) * 48 + (X0 / 8 + bj);
    cval[ci] = bv;
    cpos[ci] = bp;
  }
}

// ---------------------------------------------------------------------------
// STAGE 3: topk radix-select (blocks 0..15, hides under gemm) || fp8
// Gram-GEMM relu-sum (16..2191), swizzled LDS + XCD-chunked order.
// One 32768-byte LDS union -> 5 blocks/CU.
// ---------------------------------------------------------------------------
__global__ __launch_bounds__(256) void stage3_kernel(const float* __restrict__ cval,
                                                     const unsigned* __restrict__ cpos,
                                                     const float* __restrict__ sd,
                                                     float* __restrict__ pcorn,
                                                     const unsigned char* __restrict__ descF8,
                                                     const float* __restrict__ invn,
                                                     float* __restrict__ pgemm) {
  alignas(16) __shared__ char smem[32768];
  int tid = threadIdx.x;

  if (blockIdx.x < 16) {
    // ---- topk radix-select for batch b ----
    int* hist = (int*)smem;                      // 1024 B
    int* pick = (int*)(smem + 1024);             // 8 B
    int* eqcnt = (int*)(smem + 1032);            // 4 B
    int* ri = (int*)(smem + 1040);               // 16 B
    unsigned* eqpos = (unsigned*)(smem + 1056);  // 1024 B
    float* r4 = (float*)(smem + 2080);           // 16 B

    int b = blockIdx.x;
    int t = tid;
    int lane = t & 63;

    unsigned bits[9], pos[9];
#pragma unroll
    for (int q = 0; q < 9; q++) {
      int i = t + q * 256;
      unsigned vb = 0, p = 0;
      if (i < 2304) {
        float v = cval[b * 2304 + i];
        if (v > 0.f) { vb = __float_as_uint(v); p = cpos[b * 2304 + i]; }
      }
      bits[q] = vb; pos[q] = p;
    }

    int P = 0;
#pragma unroll
    for (int q = 0; q < 9; q++) P += (bits[q] != 0u);
    for (int off = 32; off; off >>= 1) P += __shfl_down(P, off, 64);
    if (lane == 0) ri[t >> 6] = P;
    __syncthreads();
    int Ptot = ri[0] + ri[1] + ri[2] + ri[3];
    if (Ptot == 0) { if (t == 0) pcorn[b] = 0.f; return; }
    int K = Ptot < 200 ? Ptot : 200;

    unsigned prefix = 0;
    int krem = K;
    for (int shift = 24; shift >= 0; shift -= 8) {
      hist[t] = 0;
      __syncthreads();
#pragma unroll
      for (int q = 0; q < 9; q++) {
        if (bits[q] != 0u &&
            (shift == 24 || (bits[q] >> (shift + 8)) == (prefix >> (shift + 8))))
          atomicAdd(&hist[(bits[q] >> shift) & 0xFF], 1);
      }
      __syncthreads();
      if (t < 64) {
        int h0 = hist[4 * t], h1 = hist[4 * t + 1], h2 = hist[4 * t + 2], h3 = hist[4 * t + 3];
        int tot = h0 + h1 + h2 + h3;
        int acc = tot;
        for (int d = 1; d < 64; d <<= 1) {
          int o = __shfl_down(acc, d, 64);
          if (t + d < 64) acc += o;
        }
        int excl = acc - tot;
        int G3 = excl, G2 = excl + h3, G1 = excl + h3 + h2, G0 = excl + h3 + h2 + h1;
        if (G0 < krem && G0 + h0 >= krem) { pick[0] = 4 * t;     pick[1] = G0; }
        if (G1 < krem && G1 + h1 >= krem) { pick[0] = 4 * t + 1; pick[1] = G1; }
        if (G2 < krem && G2 + h2 >= krem) { pick[0] = 4 * t + 2; pick[1] = G2; }
        if (G3 < krem && G3 + h3 >= krem) { pick[0] = 4 * t + 3; pick[1] = G3; }
      }
      __syncthreads();
      prefix |= ((unsigned)pick[0]) << shift;
      krem -= pick[1];
      __syncthreads();
    }

    if (t == 0) *eqcnt = 0;
    __syncthreads();
    float s = 0.f;
#pragma unroll
    for (int q = 0; q < 9; q++) {
      if (bits[q] > prefix) s += sd[(size_t)b * HWSZ + pos[q]];
      else if (bits[q] != 0u && bits[q] == prefix) {
        int idx = atomicAdd(eqcnt, 1);
        if (idx < 256) eqpos[idx] = pos[q];
      }
    }
    __syncthreads();
    int m = *eqcnt;
    if (m <= krem) {
      if (t < m) s += sd[(size_t)b * HWSZ + eqpos[t]];
    } else {
      int mm = m < 256 ? m : 256;
      if (t < mm) {
        unsigned p = eqpos[t];
        int rank = 0;
        for (int u = 0; u < mm; u++) rank += (eqpos[u] < p);
        if (rank < krem) s += sd[(size_t)b * HWSZ + p];
      }
    }
    for (int off = 32; off; off >>= 1) s += __shfl_down(s, off, 64);
    if (lane == 0) r4[t >> 6] = s;
    __syncthreads();
    if (t == 0) pcorn[b] = r4[0] + r4[1] + r4[2] + r4[3];
    return;
  }

  // ---- fp8 Gram-GEMM with relu-sum epilogue; swizzled LDS ----
  char* lA = smem;
  char* lB = smem + 16384;

  int bxl = blockIdx.x - 16;                // 0..2175; 16%8==0 keeps XCD map
  int bx = ((bxl & 7) * 272) + (bxl >> 3);  // contiguous 272-chunk per XCD
  int batch = bx / 136;
  int rem = bx % 136;
  int ti = 0, rowlen = 16;
  while (rem >= rowlen) { rem -= rowlen; rowlen--; ti++; }
  int tj = ti + rem;

  const unsigned char* Ab = descF8 + (size_t)batch * ND * DD;
  const float* inv = invn + batch * ND;
  int I0 = ti * 128, J0 = tj * 128;

  int wave = tid >> 6, lane = tid & 63;
  int rm = lane & 15, kq = lane >> 4;
  int wr = wave >> 1, wc = wave & 1;
  int lrow = lane >> 3;
  int lcolb = ((lane & 7) ^ lrow) << 4;   // swizzled source column (bytes)
  int cx = rm & 7;                        // read-side swizzle key

  f32x4 accf[4][4];
#pragma unroll
  for (int m = 0; m < 4; m++)
#pragma unroll
    for (int n = 0; n < 4; n++) accf[m][n] = (f32x4){0.f, 0.f, 0.f, 0.f};

  for (int k0 = 0; k0 < DD; k0 += 128) {
#pragma unroll
    for (int q = 0; q < 4; q++) {
      int chunk = wave * 4 + q;
      load_lds16(Ab + (size_t)(I0 + chunk * 8 + lrow) * DD + k0 + lcolb, lA + chunk * 1024);
      load_lds16(Ab + (size_t)(J0 + chunk * 8 + lrow) * DD + k0 + lcolb, lB + chunk * 1024);
    }
    __syncthreads();
#pragma unroll
    for (int kk = 0; kk < 128; kk += 32) {
      long af[4], bfr[4];
      int koff = kk + kq * 8;
      int pcol = ((((koff >> 4) ^ cx) << 4) | (koff & 8));
#pragma unroll
      for (int m = 0; m < 4; m++)
        af[m] = *reinterpret_cast<const long*>(lA + (wr * 64 + m * 16 + rm) * 128 + pcol);
#pragma unroll
      for (int n = 0; n < 4; n++)
        bfr[n] = *reinterpret_cast<const long*>(lB + (wc * 64 + n * 16 + rm) * 128 + pcol);
#pragma unroll
      for (int m = 0; m < 4; m++)
#pragma unroll
        for (int n = 0; n < 4; n++)
          accf[m][n] = __builtin_amdgcn_mfma_f32_16x16x32_fp8_fp8(af[m], bfr[n], accf[m][n], 0, 0, 0);
    }
    __syncthreads();
  }

  float wgt = (ti == tj) ? 1.f : 2.f;
  float invC[4];
#pragma unroll
  for (int n = 0; n < 4; n++) invC[n] = inv[J0 + wc * 64 + n * 16 + rm];
  float psum = 0.f;
#pragma unroll
  for (int m = 0; m < 4; m++) {
#pragma unroll
    for (int r = 0; r < 4; r++) {
      float invR = inv[I0 + wr * 64 + m * 16 + kq * 4 + r];
#pragma unroll
      for (int n = 0; n < 4; n++) psum += fmaxf(accf[m][n][r] * invR * invC[n], 0.f);
    }
  }
  psum *= wgt;
  for (int off = 32; off; off >>= 1) psum += __shfl_down(psum, off, 64);
  float* r4 = (float*)smem;   // overlays dead lA (k-loop ended with a barrier)
  if (lane == 0) r4[wave] = psum;
  __syncthreads();
  if (tid == 0) pgemm[bx] = r4[0] + r4[1] + r4[2] + r4[3];
}

// ---------------------------------------------------------------------------
// STAGE 4: final reduction over all partial arrays -> out[0].
// ---------------------------------------------------------------------------
__global__ __launch_bounds__(256) void finalize_kernel(const float* __restrict__ psoft,
                                                       const float* __restrict__ pcorn,
                                                       const float* __restrict__ pgemm,
                                                       float* __restrict__ out) {
  __shared__ float r4[4];
  float bce = 0.f;
  for (int i = threadIdx.x; i < 576; i += 256) bce += psoft[i];
  if (threadIdx.x < 16) bce -= pcorn[threadIdx.x];
  float g = 0.f;
  for (int i = threadIdx.x; i < 2176; i += 256) g += pgemm[i];
  float t = bce * (1.f / 2359296.f) + g * (1.f / 67108864.f);
  for (int off = 32; off; off >>= 1) t += __shfl_down(t, off, 64);
  if ((threadIdx.x & 63) == 0) r4[threadIdx.x >> 6] = t;
  __syncthreads();
  if (threadIdx.x == 0) out[0] = r4[0] + r4[1] + r4[2] + r4[3];
}

extern "C" void kernel_launch(void* const* d_in, const int* in_sizes, int n_in,
                              void* d_out, int out_size, void* d_ws, size_t ws_size,
                              hipStream_t stream) {
  (void)in_sizes; (void)n_in; (void)out_size; (void)ws_size;
  const float* desc = (const float*)d_in[0];
  const float* sd = (const float*)d_in[2];
  const float* imgs = (const float*)d_in[3];
  float* out = (float*)d_out;

  char* w = (char*)d_ws;
  float* resp = (float*)(w + OFF_RESP);
  float* cval = (float*)(w + OFF_CVAL);
  unsigned* cpos = (unsigned*)(w + OFF_CPOS);
  unsigned char* descF8 = (unsigned char*)(w + OFF_DESCB);
  float* invn = (float*)(w + OFF_INV);
  float* psoft = (float*)(w + OFF_PSOFT);
  float* pgemm = (float*)(w + OFF_PGEMM);
  float* pcorn = (float*)(w + OFF_PCORN);

  stage1_kernel<<<10496, 256, 0, stream>>>(imgs, resp, desc, descF8, invn);
  stage2_kernel<<<1728, 256, 0, stream>>>(resp, cval, cpos, (const float4*)sd, psoft);
  stage3_kernel<<<2192, 256, 0, stream>>>(cval, cpos, sd, pcorn, descF8, invn, pgemm);
  finalize_kernel<<<1, 256, 0, stream>>>(psoft, pcorn, pgemm, out);
}

// Round 14
// 150.677 us; speedup vs baseline: 1.0560x; 1.0011x over previous
//
#include <hip/hip_runtime.h>

#define H 384
#define W 384
#define HWSZ (H * W)
#define NB 16
#define ND 2048
#define DD 256

// workspace byte offsets (all 256-aligned)
#define OFF_RESP  256
#define OFF_CVAL  9437440
#define OFF_CPOS  9584896
#define OFF_DESCB 9732352     // fp8 descriptors: 16*2048*256 = 8.4 MB
#define OFF_INV   26509568
#define OFF_PSOFT 26640640    // 576 floats
#define OFF_PGEMM 26643200    // 2176 floats
#define OFF_PCORN 26652160    // 16 floats

__device__ __forceinline__ int clampi(int v) { return v < 0 ? 0 : (v > 383 ? 383 : v); }
__device__ __forceinline__ int refl(int v) { return v < 0 ? -v : (v >= 384 ? 766 - v : v); }

// fp32 -> OCP e4m3fn with RNE. Layout: [s:1][eeee:4][mmm:3] -> s<<7 | e<<3 | m.
__device__ __forceinline__ unsigned f2e4m3(float x) {
  float a = fabsf(x);
  unsigned s = (__float_as_uint(x) >> 31) << 7;
  if (a >= 448.f) return s | 0x7E;
  if (a < 0.015625f) {
    int m = (int)rintf(a * 512.f);
    return s | (unsigned)m;
  }
  unsigned u = __float_as_uint(a);
  u += 0x7FFFF + ((u >> 20) & 1);
  unsigned e = (u >> 23) - 120;
  unsigned m = (u >> 20) & 7;
  return s | (e << 3) | m;
}

typedef float f32x4 __attribute__((ext_vector_type(4)));

__device__ __forceinline__ void load_lds16(const void* g, void* l) {
  __builtin_amdgcn_global_load_lds((const __attribute__((address_space(1))) void*)g,
                                   (__attribute__((address_space(3))) void*)l, 16, 0, 0);
}

// ---------------------------------------------------------------------------
// STAGE 1: resp (blocks 0..2303) || prep_desc (blocks 2304..10495).
// vs R13: per-array phase split — ONE t-buffer [38][32] (unioned with dead
// glf) instead of three. LDS 26,448 -> 18,416 B -> 8 blocks/CU (wave max).
// __launch_bounds__(256,8) pins VGPR <= 64. Per-output fp32 chains are
// unchanged (same hgauss product order, same vgauss, same GFTT) -> bitwise
// identical; only buffer residency + barrier count change.
// ---------------------------------------------------------------------------
__global__ __launch_bounds__(256, 8) void stage1_kernel(const float* __restrict__ imgs,
                                                        float* __restrict__ resp,
                                                        const float* __restrict__ desc,
                                                        unsigned char* __restrict__ descF8,
                                                        float* __restrict__ invn) {
  __shared__ float pbuf[2964];   // pd/pe: 2 x [38][39] (dx, dy)
  __shared__ float ubuf[1640];   // union: gl[40][41] (phases 0-1) / t [38][32]
  float* pd = pbuf;
  float* pe = pbuf + 1482;
  float* glf = ubuf;             // stride 41
  float* tb = ubuf;              // stride 32

  if (blockIdx.x >= 2304) {
    // ---- prep_desc: fp32 -> fp8 e4m3 + per-row inverse norm ----
    int wave = threadIdx.x >> 6, lane = threadIdx.x & 63;
    int row = (blockIdx.x - 2304) * 4 + wave;
    const float4* src = (const float4*)(desc + (size_t)row * DD);
    float4 v = src[lane];
    unsigned pk = f2e4m3(v.x) | (f2e4m3(v.y) << 8) | (f2e4m3(v.z) << 16) | (f2e4m3(v.w) << 24);
    ((unsigned*)(descF8 + (size_t)row * DD))[lane] = pk;
    float ss = v.x * v.x + v.y * v.y + v.z * v.z + v.w * v.w;
    for (int off = 32; off; off >>= 1) ss += __shfl_down(ss, off, 64);
    if (lane == 0) invn[row] = 1.f / fmaxf(sqrtf(ss), 1e-4f);
    return;
  }

  // ---- resp: gray -> sobel(edge) -> 7x7 gauss(reflect) of products -> GFTT ----
  const float GW[7] = {0.0044330482f, 0.0540055826f, 0.2420362294f, 0.3990502160f,
                       0.2420362294f, 0.0540055826f, 0.0044330482f};
  int bid = blockIdx.x;
  int b = bid / 144;
  int t = bid % 144;
  int Y0 = (t / 12) * 32, X0 = (t % 12) * 32;
  const float* ib = imgs + (size_t)b * 3 * HWSZ;

  for (int i = threadIdx.x; i < 1600; i += 256) {
    int r = i / 40, c = i % 40;
    int gy = clampi(Y0 - 4 + r), gx = clampi(X0 - 4 + c);
    const float* p = ib + gy * W + gx;
    glf[r * 41 + c] = 0.299f * p[0] + 0.587f * p[HWSZ] + 0.114f * p[2 * HWSZ];
  }
  __syncthreads();

  bool interior = (X0 >= 32 && X0 <= 320 && Y0 >= 32 && Y0 <= 320);

  if (interior) {
    for (int i = threadIdx.x; i < 1444; i += 256) {
      int r = i / 38, c = i % 38;
      const float* g0 = glf + r * 41 + c;
      float a = g0[0],  bb = g0[1],  cc = g0[2];
      float d = g0[41],              e = g0[43];
      float f = g0[82], g = g0[83],  h = g0[84];
      float dx = 0.125f * ((cc - a) + 2.f * (e - d) + (h - f));
      float dy = 0.125f * ((f - a) + 2.f * (g - bb) + (h - cc));
      pd[r * 39 + c] = dx;
      pe[r * 39 + c] = dy;
    }
  } else {
    for (int i = threadIdx.x; i < 1444; i += 256) {
      int r = i / 38, c = i % 38;
      int py = refl(Y0 - 3 + r), px = refl(X0 - 3 + c);
      int ym = clampi(py - 1) - (Y0 - 4), y0 = py - (Y0 - 4), yp = clampi(py + 1) - (Y0 - 4);
      int xm = clampi(px - 1) - (X0 - 4), x0 = px - (X0 - 4), xp = clampi(px + 1) - (X0 - 4);
      float a = glf[ym * 41 + xm], bb = glf[ym * 41 + x0], cc = glf[ym * 41 + xp];
      float d = glf[y0 * 41 + xm], e = glf[y0 * 41 + xp];
      float f = glf[yp * 41 + xm], g = glf[yp * 41 + x0], h = glf[yp * 41 + xp];
      float dx = 0.125f * ((cc - a) + 2.f * (e - d) + (h - f));
      float dy = 0.125f * ((f - a) + 2.f * (g - bb) + (h - cc));
      pd[r * 39 + c] = dx;
      pe[r * 39 + c] = dy;
    }
  }
  __syncthreads();   // glf dead from here; tb overlays it

  int r0v = (threadIdx.x >> 5) * 4, cv = threadIdx.x & 31;
  float s0[4], s1[4], s2[4];

  // ---- array 0: dx*dx ----
  for (int g = threadIdx.x; g < 304; g += 256) {
    int r = g >> 3, c0 = (g & 7) * 4;
    float d[10];
#pragma unroll
    for (int dc = 0; dc < 10; dc++) d[dc] = pd[r * 39 + c0 + dc];
#pragma unroll
    for (int k = 0; k < 4; k++) {
      float sv = 0.f;
#pragma unroll
      for (int j = 0; j < 7; j++) sv += GW[j] * (d[k + j] * d[k + j]);
      tb[r * 32 + c0 + k] = sv;
    }
  }
  __syncthreads();
  {
    float a[10];
#pragma unroll
    for (int dr = 0; dr < 10; dr++) a[dr] = tb[(r0v + dr) * 32 + cv];
#pragma unroll
    for (int k = 0; k < 4; k++) {
      float sv = 0.f;
#pragma unroll
      for (int j = 0; j < 7; j++) sv += GW[j] * a[k + j];
      s0[k] = sv;
    }
  }
  __syncthreads();

  // ---- array 1: dy*dy ----
  for (int g = threadIdx.x; g < 304; g += 256) {
    int r = g >> 3, c0 = (g & 7) * 4;
    float e[10];
#pragma unroll
    for (int dc = 0; dc < 10; dc++) e[dc] = pe[r * 39 + c0 + dc];
#pragma unroll
    for (int k = 0; k < 4; k++) {
      float sv = 0.f;
#pragma unroll
      for (int j = 0; j < 7; j++) sv += GW[j] * (e[k + j] * e[k + j]);
      tb[r * 32 + c0 + k] = sv;
    }
  }
  __syncthreads();
  {
    float a[10];
#pragma unroll
    for (int dr = 0; dr < 10; dr++) a[dr] = tb[(r0v + dr) * 32 + cv];
#pragma unroll
    for (int k = 0; k < 4; k++) {
      float sv = 0.f;
#pragma unroll
      for (int j = 0; j < 7; j++) sv += GW[j] * a[k + j];
      s1[k] = sv;
    }
  }
  __syncthreads();

  // ---- array 2: dx*dy ----
  for (int g = threadIdx.x; g < 304; g += 256) {
    int r = g >> 3, c0 = (g & 7) * 4;
    float d[10], e[10];
#pragma unroll
    for (int dc = 0; dc < 10; dc++) {
      d[dc] = pd[r * 39 + c0 + dc];
      e[dc] = pe[r * 39 + c0 + dc];
    }
#pragma unroll
    for (int k = 0; k < 4; k++) {
      float sv = 0.f;
#pragma unroll
      for (int j = 0; j < 7; j++) sv += GW[j] * (d[k + j] * e[k + j]);
      tb[r * 32 + c0 + k] = sv;
    }
  }
  __syncthreads();
  {
    float a[10];
#pragma unroll
    for (int dr = 0; dr < 10; dr++) a[dr] = tb[(r0v + dr) * 32 + cv];
#pragma unroll
    for (int k = 0; k < 4; k++) {
      float sv = 0.f;
#pragma unroll
      for (int j = 0; j < 7; j++) sv += GW[j] * a[k + j];
      s2[k] = sv;
    }
  }

  // ---- GFTT + store ----
#pragma unroll
  for (int k = 0; k < 4; k++) {
    float tr = s0[k] + s1[k];
    float det = s0[k] * s1[k] - s2[k] * s2[k];
    float disc = tr * tr - 4.f * det;
    float rv = 0.5f * (tr - sqrtf(fabsf(disc)));
    resp[(size_t)b * HWSZ + (Y0 + r0v + k) * W + (X0 + cv)] = rv;
  }
}

// ---------------------------------------------------------------------------
// STAGE 2: nms 64x32 tiles (blocks 0..1151) || softplus (1152..1727).
// Grid MUST be 1728 (1152 nms + 576 softplus).
// ---------------------------------------------------------------------------
__global__ __launch_bounds__(256) void stage2_kernel(const float* __restrict__ resp,
                                                     float* __restrict__ cval,
                                                     unsigned* __restrict__ cpos,
                                                     const float4* __restrict__ sd4,
                                                     float* __restrict__ psoft) {
  __shared__ float rl[68][37];    // 10064 B
  __shared__ float rmx[68][32];   // 8704 B
  __shared__ float r4[4];

  if (blockIdx.x >= 1152) {
    // ---- softplus partial sums ----
    int sb = blockIdx.x - 1152;
    float s = 0.f;
    int base = sb * 256 + threadIdx.x;
#pragma unroll
    for (int it = 0; it < 4; it++) {
      float4 v = sd4[base + it * 147456];
      s += fmaxf(v.x, 0.f) + log1pf(expf(-fabsf(v.x))) +
           fmaxf(v.y, 0.f) + log1pf(expf(-fabsf(v.y))) +
           fmaxf(v.z, 0.f) + log1pf(expf(-fabsf(v.z))) +
           fmaxf(v.w, 0.f) + log1pf(expf(-fabsf(v.w)));
    }
    for (int off = 32; off; off >>= 1) s += __shfl_down(s, off, 64);
    if ((threadIdx.x & 63) == 0) r4[threadIdx.x >> 6] = s;
    __syncthreads();
    if (threadIdx.x == 0) psoft[sb] = r4[0] + r4[1] + r4[2] + r4[3];
    return;
  }

  // ---- 5x5 NMS, 64x32 tile (-inf border), separable max ----
  int bid = blockIdx.x;
  int b = bid / 72;
  int t = bid % 72;
  int Y0 = (t / 12) * 64, X0 = (t % 12) * 32;
  const float* rb = resp + (size_t)b * HWSZ;

  for (int i = threadIdx.x; i < 68 * 36; i += 256) {
    int r = i / 36, c = i % 36;
    int gy = Y0 - 2 + r, gx = X0 - 2 + c;
    float v = -INFINITY;
    if (gy >= 0 && gy < H && gx >= 0 && gx < W) v = rb[gy * W + gx];
    rl[r][c] = v;
  }
  __syncthreads();

  // horizontal 5-max: 68 rows x 32 output cols
  for (int i = threadIdx.x; i < 68 * 32; i += 256) {
    int r = i / 32, c = i % 32;
    float m = rl[r][c];
    m = fmaxf(m, rl[r][c + 1]);
    m = fmaxf(m, rl[r][c + 2]);
    m = fmaxf(m, rl[r][c + 3]);
    m = fmaxf(m, rl[r][c + 4]);
    rmx[r][c] = m;
  }
  __syncthreads();

  // vertical 5-max + nms verdict written in place into rl's center
  for (int i = threadIdx.x; i < 2048; i += 256) {
    int r = i / 32, c = i % 32;
    float m = rmx[r][c];
    m = fmaxf(m, rmx[r + 1][c]);
    m = fmaxf(m, rmx[r + 2][c]);
    m = fmaxf(m, rmx[r + 3][c]);
    m = fmaxf(m, rmx[r + 4][c]);
    float v = rl[r + 2][c + 2];
    rl[r + 2][c + 2] = (v == m) ? v : 0.f;
  }
  __syncthreads();

  if (threadIdx.x < 32) {
    int bi = threadIdx.x >> 2, bj = threadIdx.x & 3;   // 8x4 sub-blocks of 8x8
    float bv = 0.f;
    unsigned bp = 0;
    for (int rr = 0; rr < 8; rr++)
      for (int cc = 0; cc < 8; cc++) {
        float v = rl[bi * 8 + rr + 2][bj * 8 + cc + 2];
        if (v > bv) { bv = v; bp = (unsigned)((Y0 + bi * 8 + rr) * W + (X0 + bj * 8 + cc)); }
      }
    int ci = b * 2304 + (Y0 / 8 + bi) * 48 + (X0 / 8 + bj);
    cval[ci] = bv;
    cpos[ci] = bp;
  }
}

// ---------------------------------------------------------------------------
// STAGE 3: topk radix-select (blocks 0..15, hides under gemm) || fp8
// Gram-GEMM relu-sum (16..2191), swizzled LDS + XCD-chunked order.
// One 32768-byte LDS union -> 5 blocks/CU.
// ---------------------------------------------------------------------------
__global__ __launch_bounds__(256) void stage3_kernel(const float* __restrict__ cval,
                                                     const unsigned* __restrict__ cpos,
                                                     const float* __restrict__ sd,
                                                     float* __restrict__ pcorn,
                                                     const unsigned char* __restrict__ descF8,
                                                     const float* __restrict__ invn,
                                                     float* __restrict__ pgemm) {
  alignas(16) __shared__ char smem[32768];
  int tid = threadIdx.x;

  if (blockIdx.x < 16) {
    // ---- topk radix-select for batch b ----
    int* hist = (int*)smem;                      // 1024 B
    int* pick = (int*)(smem + 1024);             // 8 B
    int* eqcnt = (int*)(smem + 1032);            // 4 B
    int* ri = (int*)(smem + 1040);               // 16 B
    unsigned* eqpos = (unsigned*)(smem + 1056);  // 1024 B
    float* r4 = (float*)(smem + 2080);           // 16 B

    int b = blockIdx.x;
    int t = tid;
    int lane = t & 63;

    unsigned bits[9], pos[9];
#pragma unroll
    for (int q = 0; q < 9; q++) {
      int i = t + q * 256;
      unsigned vb = 0, p = 0;
      if (i < 2304) {
        float v = cval[b * 2304 + i];
        if (v > 0.f) { vb = __float_as_uint(v); p = cpos[b * 2304 + i]; }
      }
      bits[q] = vb; pos[q] = p;
    }

    int P = 0;
#pragma unroll
    for (int q = 0; q < 9; q++) P += (bits[q] != 0u);
    for (int off = 32; off; off >>= 1) P += __shfl_down(P, off, 64);
    if (lane == 0) ri[t >> 6] = P;
    __syncthreads();
    int Ptot = ri[0] + ri[1] + ri[2] + ri[3];
    if (Ptot == 0) { if (t == 0) pcorn[b] = 0.f; return; }
    int K = Ptot < 200 ? Ptot : 200;

    unsigned prefix = 0;
    int krem = K;
    for (int shift = 24; shift >= 0; shift -= 8) {
      hist[t] = 0;
      __syncthreads();
#pragma unroll
      for (int q = 0; q < 9; q++) {
        if (bits[q] != 0u &&
            (shift == 24 || (bits[q] >> (shift + 8)) == (prefix >> (shift + 8))))
          atomicAdd(&hist[(bits[q] >> shift) & 0xFF], 1);
      }
      __syncthreads();
      if (t < 64) {
        int h0 = hist[4 * t], h1 = hist[4 * t + 1], h2 = hist[4 * t + 2], h3 = hist[4 * t + 3];
        int tot = h0 + h1 + h2 + h3;
        int acc = tot;
        for (int d = 1; d < 64; d <<= 1) {
          int o = __shfl_down(acc, d, 64);
          if (t + d < 64) acc += o;
        }
        int excl = acc - tot;
        int G3 = excl, G2 = excl + h3, G1 = excl + h3 + h2, G0 = excl + h3 + h2 + h1;
        if (G0 < krem && G0 + h0 >= krem) { pick[0] = 4 * t;     pick[1] = G0; }
        if (G1 < krem && G1 + h1 >= krem) { pick[0] = 4 * t + 1; pick[1] = G1; }
        if (G2 < krem && G2 + h2 >= krem) { pick[0] = 4 * t + 2; pick[1] = G2; }
        if (G3 < krem && G3 + h3 >= krem) { pick[0] = 4 * t + 3; pick[1] = G3; }
      }
      __syncthreads();
      prefix |= ((unsigned)pick[0]) << shift;
      krem -= pick[1];
      __syncthreads();
    }

    if (t == 0) *eqcnt = 0;
    __syncthreads();
    float s = 0.f;
#pragma unroll
    for (int q = 0; q < 9; q++) {
      if (bits[q] > prefix) s += sd[(size_t)b * HWSZ + pos[q]];
      else if (bits[q] != 0u && bits[q] == prefix) {
        int idx = atomicAdd(eqcnt, 1);
        if (idx < 256) eqpos[idx] = pos[q];
      }
    }
    __syncthreads();
    int m = *eqcnt;
    if (m <= krem) {
      if (t < m) s += sd[(size_t)b * HWSZ + eqpos[t]];
    } else {
      int mm = m < 256 ? m : 256;
      if (t < mm) {
        unsigned p = eqpos[t];
        int rank = 0;
        for (int u = 0; u < mm; u++) rank += (eqpos[u] < p);
        if (rank < krem) s += sd[(size_t)b * HWSZ + p];
      }
    }
    for (int off = 32; off; off >>= 1) s += __shfl_down(s, off, 64);
    if (lane == 0) r4[t >> 6] = s;
    __syncthreads();
    if (t == 0) pcorn[b] = r4[0] + r4[1] + r4[2] + r4[3];
    return;
  }

  // ---- fp8 Gram-GEMM with relu-sum epilogue; swizzled LDS ----
  char* lA = smem;
  char* lB = smem + 16384;

  int bxl = blockIdx.x - 16;                // 0..2175; 16%8==0 keeps XCD map
  int bx = ((bxl & 7) * 272) + (bxl >> 3);  // contiguous 272-chunk per XCD
  int batch = bx / 136;
  int rem = bx % 136;
  int ti = 0, rowlen = 16;
  while (rem >= rowlen) { rem -= rowlen; rowlen--; ti++; }
  int tj = ti + rem;

  const unsigned char* Ab = descF8 + (size_t)batch * ND * DD;
  const float* inv = invn + batch * ND;
  int I0 = ti * 128, J0 = tj * 128;

  int wave = tid >> 6, lane = tid & 63;
  int rm = lane & 15, kq = lane >> 4;
  int wr = wave >> 1, wc = wave & 1;
  int lrow = lane >> 3;
  int lcolb = ((lane & 7) ^ lrow) << 4;   // swizzled source column (bytes)
  int cx = rm & 7;                        // read-side swizzle key

  f32x4 accf[4][4];
#pragma unroll
  for (int m = 0; m < 4; m++)
#pragma unroll
    for (int n = 0; n < 4; n++) accf[m][n] = (f32x4){0.f, 0.f, 0.f, 0.f};

  for (int k0 = 0; k0 < DD; k0 += 128) {
#pragma unroll
    for (int q = 0; q < 4; q++) {
      int chunk = wave * 4 + q;
      load_lds16(Ab + (size_t)(I0 + chunk * 8 + lrow) * DD + k0 + lcolb, lA + chunk * 1024);
      load_lds16(Ab + (size_t)(J0 + chunk * 8 + lrow) * DD + k0 + lcolb, lB + chunk * 1024);
    }
    __syncthreads();
#pragma unroll
    for (int kk = 0; kk < 128; kk += 32) {
      long af[4], bfr[4];
      int koff = kk + kq * 8;
      int pcol = ((((koff >> 4) ^ cx) << 4) | (koff & 8));
#pragma unroll
      for (int m = 0; m < 4; m++)
        af[m] = *reinterpret_cast<const long*>(lA + (wr * 64 + m * 16 + rm) * 128 + pcol);
#pragma unroll
      for (int n = 0; n < 4; n++)
        bfr[n] = *reinterpret_cast<const long*>(lB + (wc * 64 + n * 16 + rm) * 128 + pcol);
#pragma unroll
      for (int m = 0; m < 4; m++)
#pragma unroll
        for (int n = 0; n < 4; n++)
          accf[m][n] = __builtin_amdgcn_mfma_f32_16x16x32_fp8_fp8(af[m], bfr[n], accf[m][n], 0, 0, 0);
    }
    __syncthreads();
  }

  float wgt = (ti == tj) ? 1.f : 2.f;
  float invC[4];
#pragma unroll
  for (int n = 0; n < 4; n++) invC[n] = inv[J0 + wc * 64 + n * 16 + rm];
  float psum = 0.f;
#pragma unroll
  for (int m = 0; m < 4; m++) {
#pragma unroll
    for (int r = 0; r < 4; r++) {
      float invR = inv[I0 + wr * 64 + m * 16 + kq * 4 + r];
#pragma unroll
      for (int n = 0; n < 4; n++) psum += fmaxf(accf[m][n][r] * invR * invC[n], 0.f);
    }
  }
  psum *= wgt;
  for (int off = 32; off; off >>= 1) psum += __shfl_down(psum, off, 64);
  float* r4 = (float*)smem;   // overlays dead lA (k-loop ended with a barrier)
  if (lane == 0) r4[wave] = psum;
  __syncthreads();
  if (tid == 0) pgemm[bx] = r4[0] + r4[1] + r4[2] + r4[3];
}

// ---------------------------------------------------------------------------
// STAGE 4: final reduction over all partial arrays -> out[0].
// ---------------------------------------------------------------------------
__global__ __launch_bounds__(256) void finalize_kernel(const float* __restrict__ psoft,
                                                       const float* __restrict__ pcorn,
                                                       const float* __restrict__ pgemm,
                                                       float* __restrict__ out) {
  __shared__ float r4[4];
  float bce = 0.f;
  for (int i = threadIdx.x; i < 576; i += 256) bce += psoft[i];
  if (threadIdx.x < 16) bce -= pcorn[threadIdx.x];
  float g = 0.f;
  for (int i = threadIdx.x; i < 2176; i += 256) g += pgemm[i];
  float t = bce * (1.f / 2359296.f) + g * (1.f / 67108864.f);
  for (int off = 32; off; off >>= 1) t += __shfl_down(t, off, 64);
  if ((threadIdx.x & 63) == 0) r4[threadIdx.x >> 6] = t;
  __syncthreads();
  if (threadIdx.x == 0) out[0] = r4[0] + r4[1] + r4[2] + r4[3];
}

extern "C" void kernel_launch(void* const* d_in, const int* in_sizes, int n_in,
                              void* d_out, int out_size, void* d_ws, size_t ws_size,
                              hipStream_t stream) {
  (void)in_sizes; (void)n_in; (void)out_size; (void)ws_size;
  const float* desc = (const float*)d_in[0];
  const float* sd = (const float*)d_in[2];
  const float* imgs = (const float*)d_in[3];
  float* out = (float*)d_out;

  char* w = (char*)d_ws;
  float* resp = (float*)(w + OFF_RESP);
  float* cval = (float*)(w + OFF_CVAL);
  unsigned* cpos = (unsigned*)(w + OFF_CPOS);
  unsigned char* descF8 = (unsigned char*)(w + OFF_DESCB);
  float* invn = (float*)(w + OFF_INV);
  float* psoft = (float*)(w + OFF_PSOFT);
  float* pgemm = (float*)(w + OFF_PGEMM);
  float* pcorn = (float*)(w + OFF_PCORN);

  stage1_kernel<<<10496, 256, 0, stream>>>(imgs, resp, desc, descF8, invn);
  stage2_kernel<<<1728, 256, 0, stream>>>(resp, cval, cpos, (const float4*)sd, psoft);
  stage3_kernel<<<2192, 256, 0, stream>>>(cval, cpos, sd, pcorn, descF8, invn, pgemm);
  finalize_kernel<<<1, 256, 0, stream>>>(psoft, pcorn, pgemm, out);
}